// Round 8
// baseline (454.286 us; speedup 1.0000x reference)
//
#include <hip/hip_runtime.h>
#include <hip/hip_bf16.h>
#include <math.h>

// Problem constants
constexpr int B_ = 8;
constexpr int L_ = 2048;
constexpr int S_ = 1000;
constexpr int D_ = 1024;
constexpr int H_ = 8;
constexpr int E_ = 128;     // D/H
constexpr int TOPK_ = 10;
// (1/sqrt(E)) * log2(e): scores in log2 domain so p = exp2(sc)
constexpr float SCALE_LOG2E_ = 0.12751744f;

typedef __attribute__((ext_vector_type(8))) short short8;   // 8 x bf16 (4 VGPRs)
typedef __attribute__((ext_vector_type(4))) float f32x4;

__device__ inline unsigned short f2bf(float x) {            // RTN-even f32->bf16
    unsigned u = __float_as_uint(x);
    unsigned r = (u + 0x7fffu + ((u >> 16) & 1u)) >> 16;
    return (unsigned short)r;
}
__device__ inline float bf2f(unsigned short s) {
    return __uint_as_float(((unsigned)s) << 16);
}

// fast 2^x (raw v_exp_f32; inputs are |x| < 60 here)
__device__ __forceinline__ float fexp2(float x) {
#if __has_builtin(__builtin_amdgcn_exp2f)
    return __builtin_amdgcn_exp2f(x);
#else
    return __expf(x * 0.69314718056f);
#endif
}

// global -> LDS direct DMA, 16 bytes per lane (m97/m173 pattern).
// LDS dest is linear (wave-uniform base + lane*16); swizzle comes from
// pre-swizzling the per-lane GLOBAL address (bijective per row).
typedef __attribute__((address_space(1))) const unsigned int gas_u32;
typedef __attribute__((address_space(3))) unsigned int las_u32;
__device__ __forceinline__ void gload_lds16(const void* g, void* l) {
    __builtin_amdgcn_global_load_lds((gas_u32*)g, (las_u32*)l, 16, 0, 0);
}

// ---------------------------------------------------------------------------
// Generic f32 GEMM + bias (used only for the tiny 80x1024 output GEMM)
// ---------------------------------------------------------------------------
__global__ __launch_bounds__(256) void gemm_bias_kernel(
    const float* __restrict__ A, const float* __restrict__ Bm,
    const float* __restrict__ bias, float* __restrict__ C,
    int M, int N, int Kd)
{
    __shared__ float As[16][65];
    __shared__ float Bs[16][68];

    const int t  = threadIdx.x;
    const int tx = t & 15;
    const int ty = t >> 4;
    const int m0 = blockIdx.y * 64;
    const int n0 = blockIdx.x * 64;

    float acc[4][4];
#pragma unroll
    for (int i = 0; i < 4; ++i)
#pragma unroll
        for (int j = 0; j < 4; ++j) acc[i][j] = 0.f;

    for (int k0 = 0; k0 < Kd; k0 += 16) {
        {
            const int row = t >> 2;
            const int c4  = (t & 3) * 4;
            float4 v = {0.f, 0.f, 0.f, 0.f};
            if (m0 + row < M)
                v = *(const float4*)&A[(size_t)(m0 + row) * Kd + k0 + c4];
            As[c4 + 0][row] = v.x;
            As[c4 + 1][row] = v.y;
            As[c4 + 2][row] = v.z;
            As[c4 + 3][row] = v.w;
        }
        {
            const int row = t >> 4;
            const int c4  = (t & 15) * 4;
            float4 v = *(const float4*)&Bm[(size_t)(k0 + row) * N + n0 + c4];
            *(float4*)&Bs[row][c4] = v;
        }
        __syncthreads();
#pragma unroll
        for (int k = 0; k < 16; ++k) {
            float a[4], b[4];
#pragma unroll
            for (int i = 0; i < 4; ++i) a[i] = As[k][ty * 4 + i];
            float4 bv = *(const float4*)&Bs[k][tx * 4];
            b[0] = bv.x; b[1] = bv.y; b[2] = bv.z; b[3] = bv.w;
#pragma unroll
            for (int i = 0; i < 4; ++i)
#pragma unroll
                for (int j = 0; j < 4; ++j) acc[i][j] += a[i] * b[j];
        }
        __syncthreads();
    }

#pragma unroll
    for (int i = 0; i < 4; ++i) {
        const int row = m0 + ty * 4 + i;
        if (row < M) {
#pragma unroll
            for (int j = 0; j < 4; ++j) {
                const int col = n0 + tx * 4 + j;
                C[(size_t)row * N + col] = acc[i][j] + bias[col];
            }
        }
    }
}

// ---------------------------------------------------------------------------
// WT split (transpose + hi/lo): WTh/WTl[n][k] = split(W[k][n]). (r2-proven)
// ---------------------------------------------------------------------------
__global__ __launch_bounds__(256) void splitWT_kernel(
    const float* __restrict__ W,
    unsigned short* __restrict__ WTh, unsigned short* __restrict__ WTl)
{
    __shared__ __attribute__((aligned(16))) float tile[64][68];
    const int t  = threadIdx.x;
    const int k0 = blockIdx.y * 64, n0 = blockIdx.x * 64;
#pragma unroll
    for (int it = 0; it < 4; ++it) {
        int id = it * 256 + t;
        int r = id >> 4, c = id & 15;
        *(float4*)&tile[r][c * 4] = *(const float4*)&W[(size_t)(k0 + r) * D_ + n0 + c * 4];
    }
    __syncthreads();
#pragma unroll
    for (int it = 0; it < 4; ++it) {
        int id = it * 256 + t;
        int n = id >> 4, c = id & 15;
        unsigned short hs[4], ls[4];
#pragma unroll
        for (int i = 0; i < 4; ++i) {
            float x = tile[c * 4 + i][n];
            hs[i] = f2bf(x);
            ls[i] = f2bf(x - bf2f(hs[i]));
        }
        size_t o = (size_t)(n0 + n) * D_ + k0 + c * 4;
        uint2 uh; uh.x = (unsigned)hs[0] | ((unsigned)hs[1] << 16);
                  uh.y = (unsigned)hs[2] | ((unsigned)hs[3] << 16);
        uint2 ul; ul.x = (unsigned)ls[0] | ((unsigned)ls[1] << 16);
                  ul.y = (unsigned)ls[2] | ((unsigned)ls[3] << 16);
        *(uint2*)&WTh[o] = uh;
        *(uint2*)&WTl[o] = ul;
    }
}

// ---------------------------------------------------------------------------
// src split: Sh/Sl[1024(pad)][1024] bf16 hi/lo; rows >= 1000 zeroed.
// ---------------------------------------------------------------------------
__global__ __launch_bounds__(256) void split_src_kernel(
    const float* __restrict__ src,
    unsigned short* __restrict__ Sh, unsigned short* __restrict__ Sl)
{
    int idx  = blockIdx.x * 256 + threadIdx.x;
    int base = idx * 4;
    int row  = base >> 10;
    float4 v = {0.f, 0.f, 0.f, 0.f};
    if (row < S_) v = *(const float4*)&src[base];
    float xs[4] = {v.x, v.y, v.z, v.w};
    unsigned short hs[4], ls[4];
#pragma unroll
    for (int i = 0; i < 4; ++i) {
        hs[i] = f2bf(xs[i]);
        ls[i] = f2bf(xs[i] - bf2f(hs[i]));
    }
    uint2 uh; uh.x = (unsigned)hs[0] | ((unsigned)hs[1] << 16);
              uh.y = (unsigned)hs[2] | ((unsigned)hs[3] << 16);
    uint2 ul; ul.x = (unsigned)ls[0] | ((unsigned)ls[1] << 16);
              ul.y = (unsigned)ls[2] | ((unsigned)ls[3] << 16);
    *(uint2*)&Sh[base] = uh;
    *(uint2*)&Sl[base] = ul;
}

// ---------------------------------------------------------------------------
// tgt split (per batch-chunk, no padding): Th/Tl = hi/lo bf16 planes.
// n4 = number of float4 groups in the chunk.
// ---------------------------------------------------------------------------
__global__ __launch_bounds__(256) void split_tgt_kernel(
    const float* __restrict__ tgt,
    unsigned short* __restrict__ Th, unsigned short* __restrict__ Tl)
{
    int idx  = blockIdx.x * 256 + threadIdx.x;
    int base = idx * 4;
    float4 v = *(const float4*)&tgt[base];
    float xs[4] = {v.x, v.y, v.z, v.w};
    unsigned short hs[4], ls[4];
#pragma unroll
    for (int i = 0; i < 4; ++i) {
        hs[i] = f2bf(xs[i]);
        ls[i] = f2bf(xs[i] - bf2f(hs[i]));
    }
    uint2 uh; uh.x = (unsigned)hs[0] | ((unsigned)hs[1] << 16);
              uh.y = (unsigned)hs[2] | ((unsigned)hs[3] << 16);
    uint2 ul; ul.x = (unsigned)ls[0] | ((unsigned)ls[1] << 16);
              ul.y = (unsigned)ls[2] | ((unsigned)ls[3] << 16);
    *(uint2*)&Th[base] = uh;
    *(uint2*)&Tl[base] = ul;
}

// ---------------------------------------------------------------------------
// K projection via 3-term split-bf16 MFMA (r7-proven, all-DMA staging).
// Writes Kbuf (f32, path to output) AND Kh/Kl (hi/lo, pad rows zero).
// ---------------------------------------------------------------------------
__global__ __launch_bounds__(256, 2) void kproj_kernel(
    const unsigned short* __restrict__ Sh, const unsigned short* __restrict__ Sl,
    const unsigned short* __restrict__ WkTh, const unsigned short* __restrict__ WkTl,
    const float* __restrict__ bk,
    float* __restrict__ Kbuf,
    unsigned short* __restrict__ Kh, unsigned short* __restrict__ Kl)
{
    __shared__ __attribute__((aligned(16))) unsigned short Ah[128 * 64];
    __shared__ __attribute__((aligned(16))) unsigned short Al[128 * 64];
    __shared__ __attribute__((aligned(16))) unsigned short Bh[128 * 64];
    __shared__ __attribute__((aligned(16))) unsigned short Bl[128 * 64];

    const int t    = threadIdx.x;
    const int lane = t & 63, w = t >> 6;
    const int mb   = blockIdx.x >> 3;
    const int n0   = (blockIdx.x & 7) * 128;

    f32x4 acc[2][8];
#pragma unroll
    for (int m = 0; m < 2; ++m)
#pragma unroll
        for (int n = 0; n < 8; ++n) acc[m][n] = (f32x4){0.f, 0.f, 0.f, 0.f};

    for (int k0 = 0; k0 < D_; k0 += 64) {
        __syncthreads();
#pragma unroll
        for (int it = 0; it < 4; ++it) {   // DMA all 4 planes, swizzled src
            int r = it * 32 + (t >> 3), c = t & 7;
            size_t gofs = (size_t)r * D_ + k0 + ((c ^ (r & 7)) << 3);
            int db = it * 4096 + t * 16;
            gload_lds16(&Sh[(size_t)(mb * 128) * D_ + gofs], (char*)Ah + db);
            gload_lds16(&Sl[(size_t)(mb * 128) * D_ + gofs], (char*)Al + db);
            gload_lds16(&WkTh[(size_t)n0 * D_ + gofs], (char*)Bh + db);
            gload_lds16(&WkTl[(size_t)n0 * D_ + gofs], (char*)Bl + db);
        }
        __syncthreads();

#pragma unroll
        for (int ki = 0; ki < 2; ++ki) {
            short8 ah[2], al[2];
#pragma unroll
            for (int m = 0; m < 2; ++m) {
                int r = w * 32 + m * 16 + (lane & 15);
                int slot = ki * 4 + (lane >> 4);
                int lofs = r * 64 + ((slot ^ (r & 7)) << 3);
                ah[m] = *(short8*)&Ah[lofs];
                al[m] = *(short8*)&Al[lofs];
            }
#pragma unroll
            for (int n = 0; n < 8; ++n) {
                int nn = n * 16 + (lane & 15);
                int slot = ki * 4 + (lane >> 4);
                int lofs = nn * 64 + ((slot ^ (nn & 7)) << 3);
                short8 bh = *(short8*)&Bh[lofs];
                short8 bl = *(short8*)&Bl[lofs];
#pragma unroll
                for (int m = 0; m < 2; ++m) {
                    acc[m][n] = __builtin_amdgcn_mfma_f32_16x16x32_bf16(ah[m], bh, acc[m][n], 0, 0, 0);
                    acc[m][n] = __builtin_amdgcn_mfma_f32_16x16x32_bf16(ah[m], bl, acc[m][n], 0, 0, 0);
                    acc[m][n] = __builtin_amdgcn_mfma_f32_16x16x32_bf16(al[m], bh, acc[m][n], 0, 0, 0);
                }
            }
        }
    }

#pragma unroll
    for (int n = 0; n < 8; ++n) {
        int col = n0 + n * 16 + (lane & 15);
        float bkv = bk[col];
#pragma unroll
        for (int m = 0; m < 2; ++m) {
            int rbase = mb * 128 + w * 32 + m * 16 + ((lane >> 4) << 2);
#pragma unroll
            for (int r = 0; r < 4; ++r) {
                int row = rbase + r;
                unsigned short hh = 0, ll = 0;
                if (row < S_) {
                    float kv = acc[m][n][r] + bkv;
                    Kbuf[(size_t)row * D_ + col] = kv;
                    hh = f2bf(kv);
                    ll = f2bf(kv - bf2f(hh));
                }
                Kh[(size_t)row * D_ + col] = hh;
                Kl[(size_t)row * D_ + col] = ll;
            }
        }
    }
}

// ---------------------------------------------------------------------------
// Q projection v3: 3-term split, all 4 planes (tgt hi/lo pre-split, WqT
// hi/lo) via global_load_lds; BK=32, double-buffered, ONE barrier per tile.
// DMA of tile k+1 flies under the 48 MFMAs of tile k. Zero staging VALU.
// Output: planar q hi/lo bf16 with SCALE*log2(e) baked in.
// ---------------------------------------------------------------------------
__global__ __launch_bounds__(256, 2) void qproj_kernel(
    const unsigned short* __restrict__ Th, const unsigned short* __restrict__ Tl,
    const unsigned short* __restrict__ WqTh, const unsigned short* __restrict__ WqTl,
    const float* __restrict__ bq,
    unsigned short* __restrict__ qhb, unsigned short* __restrict__ qlb)
{
    __shared__ __attribute__((aligned(16))) unsigned short Ah[2][128 * 32];
    __shared__ __attribute__((aligned(16))) unsigned short Al[2][128 * 32];
    __shared__ __attribute__((aligned(16))) unsigned short Bh[2][128 * 32];
    __shared__ __attribute__((aligned(16))) unsigned short Bl[2][128 * 32];

    const int t    = threadIdx.x;
    const int lane = t & 63, w = t >> 6;
    const int mb   = blockIdx.x >> 3;
    const int n0   = (blockIdx.x & 7) * 128;

    f32x4 acc[2][8];
#pragma unroll
    for (int m = 0; m < 2; ++m)
#pragma unroll
        for (int n = 0; n < 8; ++n) acc[m][n] = (f32x4){0.f, 0.f, 0.f, 0.f};

    // stage 32-k tile KT into buffer BUF (8 DMA issues/thread)
#define QP_ISSUE(KT, BUF)                                                   \
    do {                                                                    \
        _Pragma("unroll")                                                   \
        for (int it = 0; it < 2; ++it) {                                    \
            int id = it * 256 + t;                                          \
            int r = id >> 2, c = id & 3;                                    \
            size_t gofs = (size_t)r * D_ + (KT) * 32 + ((c ^ (r & 3)) << 3);\
            int db = it * 4096 + t * 16;                                    \
            gload_lds16(&Th[(size_t)(mb * 128) * D_ + gofs], (char*)&Ah[(BUF)][0] + db); \
            gload_lds16(&Tl[(size_t)(mb * 128) * D_ + gofs], (char*)&Al[(BUF)][0] + db); \
            gload_lds16(&WqTh[(size_t)n0 * D_ + gofs], (char*)&Bh[(BUF)][0] + db); \
            gload_lds16(&WqTl[(size_t)n0 * D_ + gofs], (char*)&Bl[(BUF)][0] + db); \
        }                                                                   \
    } while (0)

    QP_ISSUE(0, 0);
    int cur = 0;
    for (int kt = 0; kt < 32; ++kt) {
        __syncthreads();              // buf[cur] DMA drained; prior reads done
        if (kt < 31) QP_ISSUE(kt + 1, cur ^ 1);

        short8 ah[2], al[2];
#pragma unroll
        for (int m = 0; m < 2; ++m) {
            int r = w * 32 + m * 16 + (lane & 15);
            int lofs = r * 32 + ((((lane >> 4)) ^ (r & 3)) << 3);
            ah[m] = *(short8*)&Ah[cur][lofs];
            al[m] = *(short8*)&Al[cur][lofs];
        }
#pragma unroll
        for (int n = 0; n < 8; ++n) {
            int nn = n * 16 + (lane & 15);
            int lofs = nn * 32 + ((((lane >> 4)) ^ (nn & 3)) << 3);
            short8 bh = *(short8*)&Bh[cur][lofs];
            short8 bl = *(short8*)&Bl[cur][lofs];
#pragma unroll
            for (int m = 0; m < 2; ++m) {
                acc[m][n] = __builtin_amdgcn_mfma_f32_16x16x32_bf16(ah[m], bh, acc[m][n], 0, 0, 0);
                acc[m][n] = __builtin_amdgcn_mfma_f32_16x16x32_bf16(ah[m], bl, acc[m][n], 0, 0, 0);
                acc[m][n] = __builtin_amdgcn_mfma_f32_16x16x32_bf16(al[m], bh, acc[m][n], 0, 0, 0);
            }
        }
        cur ^= 1;
    }
#undef QP_ISSUE

#pragma unroll
    for (int n = 0; n < 8; ++n) {
        int col = n0 + n * 16 + (lane & 15);
        float bqv = bq[col];
#pragma unroll
        for (int m = 0; m < 2; ++m) {
            int rbase = mb * 128 + w * 32 + m * 16 + ((lane >> 4) << 2);
#pragma unroll
            for (int r = 0; r < 4; ++r) {
                float q = (acc[m][n][r] + bqv) * SCALE_LOG2E_;
                unsigned short hh = f2bf(q);
                qhb[(size_t)(rbase + r) * D_ + col] = hh;
                qlb[(size_t)(rbase + r) * D_ + col] = f2bf(q - bf2f(hh));
            }
        }
    }
}

// ---------------------------------------------------------------------------
// Scores: pass 0 computes Z with 1-term MFMA (qh*kh, Kh only staged — Z only
// needs ~1e-4 relative accuracy; per-row eps washes out of rank gaps);
// pass 1 computes p with the proven 3-term and accumulates tmps.
// K staged via global_load_lds double-buffer, 32-row tiles, 1 barrier/step.
// ---------------------------------------------------------------------------
__global__ __launch_bounds__(256, 4) void scores2p_kernel(
    const unsigned short* __restrict__ qhb, const unsigned short* __restrict__ qlb,
    const unsigned short* __restrict__ Kh, const unsigned short* __restrict__ Kl,
    float* __restrict__ tmps, int b0)
{
    __shared__ __attribute__((aligned(16))) unsigned short SH[2][32 * 128];
    __shared__ __attribute__((aligned(16))) unsigned short SL[2][32 * 128];
    __shared__ float tmps_l[1024];

    const int t    = threadIdx.x;
    const int lane = t & 63, w = t >> 6;
    const int blk  = blockIdx.x;
    const int bb   = blk >> 7;
    const int h    = (blk >> 4) & 7;
    const int lt   = blk & 15;
    const int qrow0 = bb * L_ + lt * 128;        // chunk-local
    const int bh_i  = (b0 + bb) * H_ + h;
    const int kr0   = t >> 4;       // staging: r = it*16 + kr0, chunk c = t&15
    const int kc0   = t & 15;

    for (int i = t; i < 1024; i += 256) tmps_l[i] = 0.f;

    // pass-0 staging: Kh only (2 issues/thread)
#define SC_ISSUE1(ST, BUF)                                                  \
    do {                                                                    \
        _Pragma("unroll")                                                   \
        for (int it = 0; it < 2; ++it) {                                    \
            int r = it * 16 + kr0;                                          \
            size_t g = (size_t)((ST) * 32 + r) * D_ + h * E_                \
                       + ((kc0 ^ (r & 15)) << 3);                           \
            int db = it * 4096 + t * 16;                                    \
            gload_lds16(&Kh[g], (char*)&SH[(BUF)][0] + db);                 \
        }                                                                   \
    } while (0)

    // pass-1 staging: Kh + Kl (4 issues/thread)
#define SC_ISSUE2(ST, BUF)                                                  \
    do {                                                                    \
        _Pragma("unroll")                                                   \
        for (int it = 0; it < 2; ++it) {                                    \
            int r = it * 16 + kr0;                                          \
            size_t g = (size_t)((ST) * 32 + r) * D_ + h * E_                \
                       + ((kc0 ^ (r & 15)) << 3);                           \
            int db = it * 4096 + t * 16;                                    \
            gload_lds16(&Kh[g], (char*)&SH[(BUF)][0] + db);                 \
            gload_lds16(&Kl[g], (char*)&SL[(BUF)][0] + db);                 \
        }                                                                   \
    } while (0)

    SC_ISSUE1(0, 1);                 // tile 0 DMA flies under Q staging

    // ---- stage Q (128 rows x 128 cols, hi/lo) in 4 chunks of 32 rows via
    // SH[0]/SL[0]; wave w hoists its own 32 rows when chunk == w.
    short8 qh[2][4], ql[2][4];
#pragma unroll
    for (int ch = 0; ch < 4; ++ch) {
        __syncthreads();
#pragma unroll
        for (int it = 0; it < 2; ++it) {
            int r = it * 16 + kr0;
            size_t g = (size_t)(qrow0 + ch * 32 + r) * D_ + h * E_ + kc0 * 8;
            int lofs = r * 128 + ((kc0 ^ (r & 15)) << 3);
            *(uint4*)&SH[0][lofs] = *(const uint4*)&qhb[g];
            *(uint4*)&SL[0][lofs] = *(const uint4*)&qlb[g];
        }
        __syncthreads();
        if (w == ch) {
#pragma unroll
            for (int rg = 0; rg < 2; ++rg)
#pragma unroll
                for (int ki = 0; ki < 4; ++ki) {
                    int rq = rg * 16 + (lane & 15);
                    int slot = ki * 4 + (lane >> 4);
                    int lofs = rq * 128 + ((slot ^ (rq & 15)) << 3);
                    qh[rg][ki] = *(short8*)&SH[0][lofs];
                    ql[rg][ki] = *(short8*)&SL[0][lofs];
                }
        }
    }

    float zacc[2][4];
#pragma unroll
    for (int rg = 0; rg < 2; ++rg)
#pragma unroll
        for (int r = 0; r < 4; ++r) zacc[rg][r] = 0.f;
    float invZ[2][4];

    int cur = 1;                      // tile 0 landed in buffer 1

    // ================= pass 0: Z via 1-term (qh * kh) ===================
    for (int u = 0; u < 32; ++u) {
        __syncthreads();              // DMA -> buf[cur] ready
        if (u < 31) SC_ISSUE1(u + 1, cur ^ 1);
        else        SC_ISSUE2(0, cur ^ 1);   // prefetch pass-1 tile 0

        f32x4 acc[2][2];
#pragma unroll
        for (int rg = 0; rg < 2; ++rg)
#pragma unroll
            for (int nf = 0; nf < 2; ++nf) acc[rg][nf] = (f32x4){0.f, 0.f, 0.f, 0.f};

#pragma unroll
        for (int ki = 0; ki < 4; ++ki)
#pragma unroll
            for (int nf = 0; nf < 2; ++nf) {
                int sr = nf * 16 + (lane & 15);
                int slot = ki * 4 + (lane >> 4);
                int lofs = sr * 128 + ((slot ^ (sr & 15)) << 3);
                short8 bh = *(short8*)&SH[cur][lofs];
#pragma unroll
                for (int rg = 0; rg < 2; ++rg)
                    acc[rg][nf] = __builtin_amdgcn_mfma_f32_16x16x32_bf16(qh[rg][ki], bh, acc[rg][nf], 0, 0, 0);
            }

#pragma unroll
        for (int nf = 0; nf < 2; ++nf) {
            int s = u * 32 + nf * 16 + (lane & 15);
            if (s < S_) {
#pragma unroll
                for (int rg = 0; rg < 2; ++rg)
#pragma unroll
                    for (int r = 0; r < 4; ++r)
                        zacc[rg][r] += fexp2(acc[rg][nf][r]);
            }
        }
        cur ^= 1;
    }

    // Z reduce (wave-local, no barrier needed)
#pragma unroll
    for (int rg = 0; rg < 2; ++rg)
#pragma unroll
        for (int r = 0; r < 4; ++r) {
            float z = zacc[rg][r];
            z += __shfl_xor(z, 1);
            z += __shfl_xor(z, 2);
            z += __shfl_xor(z, 4);
            z += __shfl_xor(z, 8);
            invZ[rg][r] = 1.f / z;
        }

    // ================= pass 1: p via 3-term, accumulate tmps ============
    for (int u = 0; u < 32; ++u) {
        __syncthreads();
        if (u < 31) SC_ISSUE2(u + 1, cur ^ 1);

        f32x4 acc[2][2];
#pragma unroll
        for (int rg = 0; rg < 2; ++rg)
#pragma unroll
            for (int nf = 0; nf < 2; ++nf) acc[rg][nf] = (f32x4){0.f, 0.f, 0.f, 0.f};

#pragma unroll
        for (int ki = 0; ki < 4; ++ki)
#pragma unroll
            for (int nf = 0; nf < 2; ++nf) {
                int sr = nf * 16 + (lane & 15);
                int slot = ki * 4 + (lane >> 4);
                int lofs = sr * 128 + ((slot ^ (sr & 15)) << 3);
                short8 bh = *(short8*)&SH[cur][lofs];
                short8 bl = *(short8*)&SL[cur][lofs];
#pragma unroll
                for (int rg = 0; rg < 2; ++rg) {
                    acc[rg][nf] = __builtin_amdgcn_mfma_f32_16x16x32_bf16(qh[rg][ki], bh, acc[rg][nf], 0, 0, 0);
                    acc[rg][nf] = __builtin_amdgcn_mfma_f32_16x16x32_bf16(qh[rg][ki], bl, acc[rg][nf], 0, 0, 0);
                    acc[rg][nf] = __builtin_amdgcn_mfma_f32_16x16x32_bf16(ql[rg][ki], bh, acc[rg][nf], 0, 0, 0);
                }
            }

#pragma unroll
        for (int nf = 0; nf < 2; ++nf) {
            int s = u * 32 + nf * 16 + (lane & 15);
            if (s < S_) {
                float val = 0.f;
#pragma unroll
                for (int rg = 0; rg < 2; ++rg)
#pragma unroll
                    for (int r = 0; r < 4; ++r)
                        val += fexp2(acc[rg][nf][r]) * invZ[rg][r];
                atomicAdd(&tmps_l[s], val);
            }
        }
        cur ^= 1;
    }
#undef SC_ISSUE1
#undef SC_ISSUE2

    __syncthreads();
    for (int i = t; i < S_; i += 256)
        atomicAdd(&tmps[(size_t)bh_i * S_ + i], tmps_l[i]);
}

// ---------------------------------------------------------------------------
// Top-k (k=10) per (b,h); ties -> smaller index (matches jax.lax.top_k).
// ---------------------------------------------------------------------------
__global__ __launch_bounds__(256) void topk_kernel(
    const float* __restrict__ tmps, int* __restrict__ idxs)
{
    const int bh = blockIdx.x;
    const int t  = threadIdx.x;
    __shared__ float v[S_];
    __shared__ float rv[256];
    __shared__ int   ri[256];

    for (int i = t; i < S_; i += 256) v[i] = tmps[(size_t)bh * S_ + i];
    __syncthreads();

    for (int it = 0; it < TOPK_; ++it) {
        float best = -1e38f;
        int bi = 0x7fffffff;
        for (int s = t; s < S_; s += 256) {
            const float x = v[s];
            if (x > best) { best = x; bi = s; }
        }
        rv[t] = best; ri[t] = bi;
        __syncthreads();
        for (int k = 128; k > 0; k >>= 1) {
            if (t < k) {
                const float x = rv[t + k];
                const int  xi = ri[t + k];
                if (x > rv[t] || (x == rv[t] && xi < ri[t])) { rv[t] = x; ri[t] = xi; }
            }
            __syncthreads();
        }
        if (t == 0) {
            idxs[bh * TOPK_ + it] = ri[0];
            v[ri[0]] = -1e38f;
        }
        __syncthreads();
    }
}

// ---------------------------------------------------------------------------
// Gather selected K rows into tok[b][topk][D]
// ---------------------------------------------------------------------------
__global__ __launch_bounds__(256) void gather_kernel(
    const float* __restrict__ K, const int* __restrict__ idxs,
    float* __restrict__ tok)
{
    const int o = blockIdx.x * 256 + threadIdx.x;
    if (o >= B_ * TOPK_ * D_) return;
    const int d  = o & (D_ - 1);
    const int tt = (o >> 10) % TOPK_;
    const int b  = o / (D_ * TOPK_);
    const int h  = d >> 7;
    const int s  = idxs[(b * H_ + h) * TOPK_ + tt];
    tok[o] = K[(size_t)s * D_ + d];
}

// ---------------------------------------------------------------------------
extern "C" void kernel_launch(void* const* d_in, const int* in_sizes, int n_in,
                              void* d_out, int out_size, void* d_ws, size_t ws_size,
                              hipStream_t stream)
{
    const float* tgt = (const float*)d_in[0];
    const float* src = (const float*)d_in[1];
    const float* Wq  = (const float*)d_in[2];
    const float* bq  = (const float*)d_in[3];
    const float* Wk  = (const float*)d_in[4];
    const float* bk  = (const float*)d_in[5];
    const float* Wo  = (const float*)d_in[6];
    const float* bo  = (const float*)d_in[7];
    float* out = (float*)d_out;

    // workspace layout (bytes, all 256-aligned)
    char* ws = (char*)d_ws;
    size_t off = 0;
    float*          Kbuf = (float*)(ws + off);          off += (size_t)S_ * D_ * 4;
    float*          tmps = (float*)(ws + off);          off += (size_t)B_ * H_ * S_ * 4;
    int*            idxs = (int*)(ws + off);            off += (size_t)B_ * H_ * TOPK_ * 4;
    off = (off + 255) & ~(size_t)255;
    float*          tok  = (float*)(ws + off);          off += (size_t)B_ * TOPK_ * D_ * 4;
    unsigned short* Kh   = (unsigned short*)(ws + off); off += (size_t)1024 * D_ * 2;
    unsigned short* Kl   = (unsigned short*)(ws + off); off += (size_t)1024 * D_ * 2;
    unsigned short* WqTh = (unsigned short*)(ws + off); off += (size_t)D_ * D_ * 2;
    unsigned short* WqTl = (unsigned short*)(ws + off); off += (size_t)D_ * D_ * 2;
    unsigned short* WkTh = (unsigned short*)(ws + off); off += (size_t)D_ * D_ * 2;
    unsigned short* WkTl = (unsigned short*)(ws + off); off += (size_t)D_ * D_ * 2;
    unsigned short* Sh   = (unsigned short*)(ws + off); off += (size_t)1024 * D_ * 2;
    unsigned short* Sl   = (unsigned short*)(ws + off); off += (size_t)1024 * D_ * 2;
    unsigned short* planes = (unsigned short*)(ws + off);
    const size_t fixed_bytes = off;
    const size_t plane_elems_per_b = (size_t)L_ * D_;    // per bf16 plane per batch
    // per batch: Th + Tl + qh + ql = 4 planes x 4 MB = 16 MB

    int nb_fit = 1;
    if (ws_size > fixed_bytes) {
        size_t f = (ws_size - fixed_bytes) / (4 * plane_elems_per_b * 2);
        nb_fit = (f < 1) ? 1 : (f > 8 ? 8 : (int)f);
    }

    hipMemsetAsync(tmps, 0, (size_t)B_ * H_ * S_ * sizeof(float), stream);

    split_src_kernel<<<(1024 * D_) / (256 * 4), 256, 0, stream>>>(src, Sh, Sl);
    {
        dim3 g(D_ / 64, D_ / 64);
        splitWT_kernel<<<g, 256, 0, stream>>>(Wq, WqTh, WqTl);
        splitWT_kernel<<<g, 256, 0, stream>>>(Wk, WkTh, WkTl);
    }

    // K = src @ Wk + bk via 3-term MFMA (writes Kbuf f32 + Kh/Kl bf16)
    kproj_kernel<<<64, 256, 0, stream>>>(Sh, Sl, WkTh, WkTl, bk, Kbuf, Kh, Kl);

    for (int b0 = 0; b0 < B_; b0 += nb_fit) {
        int nb = (B_ - b0 < nb_fit) ? (B_ - b0) : nb_fit;
        unsigned short* Th  = planes;
        unsigned short* Tl  = Th  + (size_t)nb_fit * plane_elems_per_b;
        unsigned short* qhb = Tl  + (size_t)nb_fit * plane_elems_per_b;
        unsigned short* qlb = qhb + (size_t)nb_fit * plane_elems_per_b;

        split_tgt_kernel<<<(unsigned)((size_t)nb * L_ * D_ / (256 * 4)), 256, 0, stream>>>(
            tgt + (size_t)b0 * L_ * D_, Th, Tl);
        qproj_kernel<<<nb * 128, 256, 0, stream>>>(Th, Tl, WqTh, WqTl, bq, qhb, qlb);
        scores2p_kernel<<<nb * 128, 256, 0, stream>>>(qhb, qlb, Kh, Kl, tmps, b0);
    }

    topk_kernel<<<B_ * H_, 256, 0, stream>>>(tmps, idxs);
    gather_kernel<<<(B_ * TOPK_ * D_ + 255) / 256, 256, 0, stream>>>(Kbuf, idxs, tok);
    {
        dim3 g(D_ / 64, (B_ * TOPK_ + 63) / 64);
        gemm_bias_kernel<<<g, 256, 0, stream>>>(tok, Wo, bo, out, B_ * TOPK_, D_, D_);
    }
}

// Round 9
// 441.552 us; speedup vs baseline: 1.0288x; 1.0288x over previous
//
#include <hip/hip_runtime.h>
#include <hip/hip_bf16.h>
#include <math.h>

// Problem constants
constexpr int B_ = 8;
constexpr int L_ = 2048;
constexpr int S_ = 1000;
constexpr int D_ = 1024;
constexpr int H_ = 8;
constexpr int E_ = 128;     // D/H
constexpr int TOPK_ = 10;
// (1/sqrt(E)) * log2(e): scores in log2 domain so p = exp2(sc)
constexpr float SCALE_LOG2E_ = 0.12751744f;

typedef __attribute__((ext_vector_type(8))) short short8;   // 8 x bf16 (4 VGPRs)
typedef __attribute__((ext_vector_type(4))) float f32x4;

__device__ inline unsigned short f2bf(float x) {            // RTN-even f32->bf16
    unsigned u = __float_as_uint(x);
    unsigned r = (u + 0x7fffu + ((u >> 16) & 1u)) >> 16;
    return (unsigned short)r;
}
__device__ inline float bf2f(unsigned short s) {
    return __uint_as_float(((unsigned)s) << 16);
}

// fast 2^x (raw v_exp_f32; inputs are |x| < 60 here)
__device__ __forceinline__ float fexp2(float x) {
#if __has_builtin(__builtin_amdgcn_exp2f)
    return __builtin_amdgcn_exp2f(x);
#else
    return __expf(x * 0.69314718056f);
#endif
}

// global -> LDS direct DMA, 16 bytes per lane (m97/m173 pattern).
// LDS dest is linear (wave-uniform base + lane*16); swizzle comes from
// pre-swizzling the per-lane GLOBAL address (bijective per row).
typedef __attribute__((address_space(1))) const unsigned int gas_u32;
typedef __attribute__((address_space(3))) unsigned int las_u32;
__device__ __forceinline__ void gload_lds16(const void* g, void* l) {
    __builtin_amdgcn_global_load_lds((gas_u32*)g, (las_u32*)l, 16, 0, 0);
}

// ---------------------------------------------------------------------------
// Generic f32 GEMM + bias (used only for the tiny 80x1024 output GEMM)
// ---------------------------------------------------------------------------
__global__ __launch_bounds__(256) void gemm_bias_kernel(
    const float* __restrict__ A, const float* __restrict__ Bm,
    const float* __restrict__ bias, float* __restrict__ C,
    int M, int N, int Kd)
{
    __shared__ float As[16][65];
    __shared__ float Bs[16][68];

    const int t  = threadIdx.x;
    const int tx = t & 15;
    const int ty = t >> 4;
    const int m0 = blockIdx.y * 64;
    const int n0 = blockIdx.x * 64;

    float acc[4][4];
#pragma unroll
    for (int i = 0; i < 4; ++i)
#pragma unroll
        for (int j = 0; j < 4; ++j) acc[i][j] = 0.f;

    for (int k0 = 0; k0 < Kd; k0 += 16) {
        {
            const int row = t >> 2;
            const int c4  = (t & 3) * 4;
            float4 v = {0.f, 0.f, 0.f, 0.f};
            if (m0 + row < M)
                v = *(const float4*)&A[(size_t)(m0 + row) * Kd + k0 + c4];
            As[c4 + 0][row] = v.x;
            As[c4 + 1][row] = v.y;
            As[c4 + 2][row] = v.z;
            As[c4 + 3][row] = v.w;
        }
        {
            const int row = t >> 4;
            const int c4  = (t & 15) * 4;
            float4 v = *(const float4*)&Bm[(size_t)(k0 + row) * N + n0 + c4];
            *(float4*)&Bs[row][c4] = v;
        }
        __syncthreads();
#pragma unroll
        for (int k = 0; k < 16; ++k) {
            float a[4], b[4];
#pragma unroll
            for (int i = 0; i < 4; ++i) a[i] = As[k][ty * 4 + i];
            float4 bv = *(const float4*)&Bs[k][tx * 4];
            b[0] = bv.x; b[1] = bv.y; b[2] = bv.z; b[3] = bv.w;
#pragma unroll
            for (int i = 0; i < 4; ++i)
#pragma unroll
                for (int j = 0; j < 4; ++j) acc[i][j] += a[i] * b[j];
        }
        __syncthreads();
    }

#pragma unroll
    for (int i = 0; i < 4; ++i) {
        const int row = m0 + ty * 4 + i;
        if (row < M) {
#pragma unroll
            for (int j = 0; j < 4; ++j) {
                const int col = n0 + tx * 4 + j;
                C[(size_t)row * N + col] = acc[i][j] + bias[col];
            }
        }
    }
}

// ---------------------------------------------------------------------------
// WT split (transpose + hi/lo): WTh/WTl[n][k] = split(W[k][n]). (r2-proven)
// ---------------------------------------------------------------------------
__global__ __launch_bounds__(256) void splitWT_kernel(
    const float* __restrict__ W,
    unsigned short* __restrict__ WTh, unsigned short* __restrict__ WTl)
{
    __shared__ __attribute__((aligned(16))) float tile[64][68];
    const int t  = threadIdx.x;
    const int k0 = blockIdx.y * 64, n0 = blockIdx.x * 64;
#pragma unroll
    for (int it = 0; it < 4; ++it) {
        int id = it * 256 + t;
        int r = id >> 4, c = id & 15;
        *(float4*)&tile[r][c * 4] = *(const float4*)&W[(size_t)(k0 + r) * D_ + n0 + c * 4];
    }
    __syncthreads();
#pragma unroll
    for (int it = 0; it < 4; ++it) {
        int id = it * 256 + t;
        int n = id >> 4, c = id & 15;
        unsigned short hs[4], ls[4];
#pragma unroll
        for (int i = 0; i < 4; ++i) {
            float x = tile[c * 4 + i][n];
            hs[i] = f2bf(x);
            ls[i] = f2bf(x - bf2f(hs[i]));
        }
        size_t o = (size_t)(n0 + n) * D_ + k0 + c * 4;
        uint2 uh; uh.x = (unsigned)hs[0] | ((unsigned)hs[1] << 16);
                  uh.y = (unsigned)hs[2] | ((unsigned)hs[3] << 16);
        uint2 ul; ul.x = (unsigned)ls[0] | ((unsigned)ls[1] << 16);
                  ul.y = (unsigned)ls[2] | ((unsigned)ls[3] << 16);
        *(uint2*)&WTh[o] = uh;
        *(uint2*)&WTl[o] = ul;
    }
}

// ---------------------------------------------------------------------------
// src split: Sh/Sl[1024(pad)][1024] bf16 hi/lo; rows >= 1000 zeroed.
// ---------------------------------------------------------------------------
__global__ __launch_bounds__(256) void split_src_kernel(
    const float* __restrict__ src,
    unsigned short* __restrict__ Sh, unsigned short* __restrict__ Sl)
{
    int idx  = blockIdx.x * 256 + threadIdx.x;
    int base = idx * 4;
    int row  = base >> 10;
    float4 v = {0.f, 0.f, 0.f, 0.f};
    if (row < S_) v = *(const float4*)&src[base];
    float xs[4] = {v.x, v.y, v.z, v.w};
    unsigned short hs[4], ls[4];
#pragma unroll
    for (int i = 0; i < 4; ++i) {
        hs[i] = f2bf(xs[i]);
        ls[i] = f2bf(xs[i] - bf2f(hs[i]));
    }
    uint2 uh; uh.x = (unsigned)hs[0] | ((unsigned)hs[1] << 16);
              uh.y = (unsigned)hs[2] | ((unsigned)hs[3] << 16);
    uint2 ul; ul.x = (unsigned)ls[0] | ((unsigned)ls[1] << 16);
              ul.y = (unsigned)ls[2] | ((unsigned)ls[3] << 16);
    *(uint2*)&Sh[base] = uh;
    *(uint2*)&Sl[base] = ul;
}

// ---------------------------------------------------------------------------
// K projection via 3-term split-bf16 MFMA (r7/r8-proven, all-DMA staging).
// Writes Kbuf (f32, path to output) AND Kh/Kl (hi/lo, pad rows zero).
// ---------------------------------------------------------------------------
__global__ __launch_bounds__(256, 2) void kproj_kernel(
    const unsigned short* __restrict__ Sh, const unsigned short* __restrict__ Sl,
    const unsigned short* __restrict__ WkTh, const unsigned short* __restrict__ WkTl,
    const float* __restrict__ bk,
    float* __restrict__ Kbuf,
    unsigned short* __restrict__ Kh, unsigned short* __restrict__ Kl)
{
    __shared__ __attribute__((aligned(16))) unsigned short Ah[128 * 64];
    __shared__ __attribute__((aligned(16))) unsigned short Al[128 * 64];
    __shared__ __attribute__((aligned(16))) unsigned short Bh[128 * 64];
    __shared__ __attribute__((aligned(16))) unsigned short Bl[128 * 64];

    const int t    = threadIdx.x;
    const int lane = t & 63, w = t >> 6;
    const int mb   = blockIdx.x >> 3;
    const int n0   = (blockIdx.x & 7) * 128;

    f32x4 acc[2][8];
#pragma unroll
    for (int m = 0; m < 2; ++m)
#pragma unroll
        for (int n = 0; n < 8; ++n) acc[m][n] = (f32x4){0.f, 0.f, 0.f, 0.f};

    for (int k0 = 0; k0 < D_; k0 += 64) {
        __syncthreads();
#pragma unroll
        for (int it = 0; it < 4; ++it) {   // DMA all 4 planes, swizzled src
            int r = it * 32 + (t >> 3), c = t & 7;
            size_t gofs = (size_t)r * D_ + k0 + ((c ^ (r & 7)) << 3);
            int db = it * 4096 + t * 16;
            gload_lds16(&Sh[(size_t)(mb * 128) * D_ + gofs], (char*)Ah + db);
            gload_lds16(&Sl[(size_t)(mb * 128) * D_ + gofs], (char*)Al + db);
            gload_lds16(&WkTh[(size_t)n0 * D_ + gofs], (char*)Bh + db);
            gload_lds16(&WkTl[(size_t)n0 * D_ + gofs], (char*)Bl + db);
        }
        __syncthreads();

#pragma unroll
        for (int ki = 0; ki < 2; ++ki) {
            short8 ah[2], al[2];
#pragma unroll
            for (int m = 0; m < 2; ++m) {
                int r = w * 32 + m * 16 + (lane & 15);
                int slot = ki * 4 + (lane >> 4);
                int lofs = r * 64 + ((slot ^ (r & 7)) << 3);
                ah[m] = *(short8*)&Ah[lofs];
                al[m] = *(short8*)&Al[lofs];
            }
#pragma unroll
            for (int n = 0; n < 8; ++n) {
                int nn = n * 16 + (lane & 15);
                int slot = ki * 4 + (lane >> 4);
                int lofs = nn * 64 + ((slot ^ (nn & 7)) << 3);
                short8 bh = *(short8*)&Bh[lofs];
                short8 bl = *(short8*)&Bl[lofs];
#pragma unroll
                for (int m = 0; m < 2; ++m) {
                    acc[m][n] = __builtin_amdgcn_mfma_f32_16x16x32_bf16(ah[m], bh, acc[m][n], 0, 0, 0);
                    acc[m][n] = __builtin_amdgcn_mfma_f32_16x16x32_bf16(ah[m], bl, acc[m][n], 0, 0, 0);
                    acc[m][n] = __builtin_amdgcn_mfma_f32_16x16x32_bf16(al[m], bh, acc[m][n], 0, 0, 0);
                }
            }
        }
    }

#pragma unroll
    for (int n = 0; n < 8; ++n) {
        int col = n0 + n * 16 + (lane & 15);
        float bkv = bk[col];
#pragma unroll
        for (int m = 0; m < 2; ++m) {
            int rbase = mb * 128 + w * 32 + m * 16 + ((lane >> 4) << 2);
#pragma unroll
            for (int r = 0; r < 4; ++r) {
                int row = rbase + r;
                unsigned short hh = 0, ll = 0;
                if (row < S_) {
                    float kv = acc[m][n][r] + bkv;
                    Kbuf[(size_t)row * D_ + col] = kv;
                    hh = f2bf(kv);
                    ll = f2bf(kv - bf2f(hh));
                }
                Kh[(size_t)row * D_ + col] = hh;
                Kl[(size_t)row * D_ + col] = ll;
            }
        }
    }
}

// ---------------------------------------------------------------------------
// Q projection v4: fused tgt split. A staged as RAW F32 via global_load_lds
// (no split_tgt kernel, no HBM round-trip); f32 -> hi/lo bf16 conversion at
// fragment-read time in registers (hides under the 48 MFMAs). B (WqT hi/lo)
// via DMA. BK=32, double-buffered, ONE barrier per tile. Numerics bitwise
// identical to r8 (same f2bf RTNE on the same f32 values).
// ---------------------------------------------------------------------------
__global__ __launch_bounds__(256, 2) void qproj_kernel(
    const float* __restrict__ tgt,   // pre-offset to chunk start
    const unsigned short* __restrict__ WqTh, const unsigned short* __restrict__ WqTl,
    const float* __restrict__ bq,
    unsigned short* __restrict__ qhb, unsigned short* __restrict__ qlb)
{
    __shared__ __attribute__((aligned(16))) float          Af[2][128 * 32];
    __shared__ __attribute__((aligned(16))) unsigned short Bh[2][128 * 32];
    __shared__ __attribute__((aligned(16))) unsigned short Bl[2][128 * 32];

    const int t    = threadIdx.x;
    const int lane = t & 63, w = t >> 6;
    const int mb   = blockIdx.x >> 3;
    const int n0   = (blockIdx.x & 7) * 128;

    f32x4 acc[2][8];
#pragma unroll
    for (int m = 0; m < 2; ++m)
#pragma unroll
        for (int n = 0; n < 8; ++n) acc[m][n] = (f32x4){0.f, 0.f, 0.f, 0.f};

    // stage 32-k tile KT into buffer BUF: A f32 (4 issues) + B hi/lo (4)
#define QP_ISSUE(KT, BUF)                                                   \
    do {                                                                    \
        _Pragma("unroll")                                                   \
        for (int it = 0; it < 4; ++it) {   /* A: 128 rows x 32 f32 */       \
            int id = it * 256 + t;                                          \
            int r = id >> 3, c = id & 7;   /* c: 16B chunk (4 f32) */       \
            size_t ga = (size_t)(mb * 128 + r) * D_ + (KT) * 32             \
                        + ((c ^ (r & 7)) << 2);                             \
            gload_lds16(&tgt[ga], (char*)&Af[(BUF)][0] + it * 4096 + t * 16); \
        }                                                                   \
        _Pragma("unroll")                                                   \
        for (int it = 0; it < 2; ++it) {   /* B: 128 rows x 32 bf16 x2 */   \
            int id = it * 256 + t;                                          \
            int r = id >> 2, c = id & 3;   /* c: 16B chunk (8 bf16) */      \
            size_t gb = (size_t)(n0 + r) * D_ + (KT) * 32                   \
                        + ((c ^ (r & 3)) << 3);                             \
            int db = it * 4096 + t * 16;                                    \
            gload_lds16(&WqTh[gb], (char*)&Bh[(BUF)][0] + db);              \
            gload_lds16(&WqTl[gb], (char*)&Bl[(BUF)][0] + db);              \
        }                                                                   \
    } while (0)

    QP_ISSUE(0, 0);
    int cur = 0;
    for (int kt = 0; kt < 32; ++kt) {
        __syncthreads();              // buf[cur] DMA drained; prior reads done
        if (kt < 31) QP_ISSUE(kt + 1, cur ^ 1);

        // A frags: read f32, convert to hi/lo in registers
        short8 ah[2], al[2];
#pragma unroll
        for (int m = 0; m < 2; ++m) {
            int r  = w * 32 + m * 16 + (lane & 15);
            int c0 = (lane >> 4) * 2;
            float4 x0 = *(float4*)&Af[cur][r * 32 + ((c0 ^ (r & 7)) << 2)];
            float4 x1 = *(float4*)&Af[cur][r * 32 + (((c0 + 1) ^ (r & 7)) << 2)];
            float xs[8] = {x0.x, x0.y, x0.z, x0.w, x1.x, x1.y, x1.z, x1.w};
#pragma unroll
            for (int j = 0; j < 8; ++j) {
                unsigned short hh = f2bf(xs[j]);
                ah[m][j] = (short)hh;
                al[m][j] = (short)f2bf(xs[j] - bf2f(hh));
            }
        }
#pragma unroll
        for (int n = 0; n < 8; ++n) {
            int nn = n * 16 + (lane & 15);
            int lofs = nn * 32 + (((lane >> 4) ^ (nn & 3)) << 3);
            short8 bh = *(short8*)&Bh[cur][lofs];
            short8 bl = *(short8*)&Bl[cur][lofs];
#pragma unroll
            for (int m = 0; m < 2; ++m) {
                acc[m][n] = __builtin_amdgcn_mfma_f32_16x16x32_bf16(ah[m], bh, acc[m][n], 0, 0, 0);
                acc[m][n] = __builtin_amdgcn_mfma_f32_16x16x32_bf16(ah[m], bl, acc[m][n], 0, 0, 0);
                acc[m][n] = __builtin_amdgcn_mfma_f32_16x16x32_bf16(al[m], bh, acc[m][n], 0, 0, 0);
            }
        }
        cur ^= 1;
    }
#undef QP_ISSUE

#pragma unroll
    for (int n = 0; n < 8; ++n) {
        int col = n0 + n * 16 + (lane & 15);
        float bqv = bq[col];
#pragma unroll
        for (int m = 0; m < 2; ++m) {
            int rbase = mb * 128 + w * 32 + m * 16 + ((lane >> 4) << 2);
#pragma unroll
            for (int r = 0; r < 4; ++r) {
                float q = (acc[m][n][r] + bqv) * SCALE_LOG2E_;
                unsigned short hh = f2bf(q);
                qhb[(size_t)(rbase + r) * D_ + col] = hh;
                qlb[(size_t)(rbase + r) * D_ + col] = f2bf(q - bf2f(hh));
            }
        }
    }
}

// ---------------------------------------------------------------------------
// Scores: pass 0 computes Z with 1-term MFMA on 64-row Kh tiles (SH half =
// rows 0-31, SL half = rows 32-63; 16 steps, half the barriers); pass 1
// computes p with the proven 3-term on 32-row Kh+Kl tiles (r8 verbatim).
// ---------------------------------------------------------------------------
__global__ __launch_bounds__(256, 4) void scores2p_kernel(
    const unsigned short* __restrict__ qhb, const unsigned short* __restrict__ qlb,
    const unsigned short* __restrict__ Kh, const unsigned short* __restrict__ Kl,
    float* __restrict__ tmps, int b0)
{
    __shared__ __attribute__((aligned(16))) unsigned short SH[2][32 * 128];
    __shared__ __attribute__((aligned(16))) unsigned short SL[2][32 * 128];
    __shared__ float tmps_l[1024];

    const int t    = threadIdx.x;
    const int lane = t & 63, w = t >> 6;
    const int blk  = blockIdx.x;
    const int bb   = blk >> 7;
    const int h    = (blk >> 4) & 7;
    const int lt   = blk & 15;
    const int qrow0 = bb * L_ + lt * 128;        // chunk-local
    const int bh_i  = (b0 + bb) * H_ + h;
    const int kr0   = t >> 4;       // staging: r = it*16 + kr0, chunk c = t&15
    const int kc0   = t & 15;

    for (int i = t; i < 1024; i += 256) tmps_l[i] = 0.f;

    // pass-0 staging: 64-row Kh tile; rows 0-31 -> SH[BUF], 32-63 -> SL[BUF]
#define SC_ISSUE0(ST, BUF)                                                  \
    do {                                                                    \
        _Pragma("unroll")                                                   \
        for (int it = 0; it < 4; ++it) {                                    \
            int r = it * 16 + kr0;                                          \
            size_t g = (size_t)((ST) * 64 + r) * D_ + h * E_                \
                       + ((kc0 ^ (r & 15)) << 3);                           \
            char* base = (it < 2) ? (char*)&SH[(BUF)][0]                    \
                                  : (char*)&SL[(BUF)][0];                   \
            int db = (it & 1) * 4096 + t * 16;                              \
            gload_lds16(&Kh[g], base + db);                                 \
        }                                                                   \
    } while (0)

    // pass-1 staging: 32-row tile, Kh + Kl (4 issues/thread)
#define SC_ISSUE2(ST, BUF)                                                  \
    do {                                                                    \
        _Pragma("unroll")                                                   \
        for (int it = 0; it < 2; ++it) {                                    \
            int r = it * 16 + kr0;                                          \
            size_t g = (size_t)((ST) * 32 + r) * D_ + h * E_                \
                       + ((kc0 ^ (r & 15)) << 3);                           \
            int db = it * 4096 + t * 16;                                    \
            gload_lds16(&Kh[g], (char*)&SH[(BUF)][0] + db);                 \
            gload_lds16(&Kl[g], (char*)&SL[(BUF)][0] + db);                 \
        }                                                                   \
    } while (0)

    SC_ISSUE0(0, 1);                 // tile 0 DMA flies under Q staging

    // ---- stage Q (128 rows x 128 cols, hi/lo) in 4 chunks of 32 rows via
    // SH[0]/SL[0]; wave w hoists its own 32 rows when chunk == w.
    short8 qh[2][4], ql[2][4];
#pragma unroll
    for (int ch = 0; ch < 4; ++ch) {
        __syncthreads();
#pragma unroll
        for (int it = 0; it < 2; ++it) {
            int r = it * 16 + kr0;
            size_t g = (size_t)(qrow0 + ch * 32 + r) * D_ + h * E_ + kc0 * 8;
            int lofs = r * 128 + ((kc0 ^ (r & 15)) << 3);
            *(uint4*)&SH[0][lofs] = *(const uint4*)&qhb[g];
            *(uint4*)&SL[0][lofs] = *(const uint4*)&qlb[g];
        }
        __syncthreads();
        if (w == ch) {
#pragma unroll
            for (int rg = 0; rg < 2; ++rg)
#pragma unroll
                for (int ki = 0; ki < 4; ++ki) {
                    int rq = rg * 16 + (lane & 15);
                    int slot = ki * 4 + (lane >> 4);
                    int lofs = rq * 128 + ((slot ^ (rq & 15)) << 3);
                    qh[rg][ki] = *(short8*)&SH[0][lofs];
                    ql[rg][ki] = *(short8*)&SL[0][lofs];
                }
        }
    }

    float zacc[2][4];
#pragma unroll
    for (int rg = 0; rg < 2; ++rg)
#pragma unroll
        for (int r = 0; r < 4; ++r) zacc[rg][r] = 0.f;
    float invZ[2][4];

    int cur = 1;                      // tile 0 landed in buffer 1

    // ============ pass 0: Z via 1-term (qh * kh), 64-row tiles ==========
    for (int u = 0; u < 16; ++u) {
        __syncthreads();              // DMA -> buf[cur] ready
        if (u < 15) SC_ISSUE0(u + 1, cur ^ 1);
        else        SC_ISSUE2(0, cur ^ 1);   // prefetch pass-1 tile 0

        f32x4 acc[2][4];
#pragma unroll
        for (int rg = 0; rg < 2; ++rg)
#pragma unroll
            for (int nf = 0; nf < 4; ++nf) acc[rg][nf] = (f32x4){0.f, 0.f, 0.f, 0.f};

#pragma unroll
        for (int ki = 0; ki < 4; ++ki)
#pragma unroll
            for (int nf = 0; nf < 4; ++nf) {
                int sr = nf * 16 + (lane & 15);       // 0..63
                int slot = ki * 4 + (lane >> 4);
                int lofs = (sr & 31) * 128 + ((slot ^ (sr & 15)) << 3);
                short8 bh = (nf < 2) ? *(short8*)&SH[cur][lofs]
                                     : *(short8*)&SL[cur][lofs];
#pragma unroll
                for (int rg = 0; rg < 2; ++rg)
                    acc[rg][nf] = __builtin_amdgcn_mfma_f32_16x16x32_bf16(qh[rg][ki], bh, acc[rg][nf], 0, 0, 0);
            }

#pragma unroll
        for (int nf = 0; nf < 4; ++nf) {
            int s = u * 64 + nf * 16 + (lane & 15);
            if (s < S_) {
#pragma unroll
                for (int rg = 0; rg < 2; ++rg)
#pragma unroll
                    for (int r = 0; r < 4; ++r)
                        zacc[rg][r] += fexp2(acc[rg][nf][r]);
            }
        }
        cur ^= 1;
    }

    // Z reduce (wave-local, no barrier needed)
#pragma unroll
    for (int rg = 0; rg < 2; ++rg)
#pragma unroll
        for (int r = 0; r < 4; ++r) {
            float z = zacc[rg][r];
            z += __shfl_xor(z, 1);
            z += __shfl_xor(z, 2);
            z += __shfl_xor(z, 4);
            z += __shfl_xor(z, 8);
            invZ[rg][r] = 1.f / z;
        }

    // ================= pass 1: p via 3-term, accumulate tmps ============
    for (int u = 0; u < 32; ++u) {
        __syncthreads();
        if (u < 31) SC_ISSUE2(u + 1, cur ^ 1);

        f32x4 acc[2][2];
#pragma unroll
        for (int rg = 0; rg < 2; ++rg)
#pragma unroll
            for (int nf = 0; nf < 2; ++nf) acc[rg][nf] = (f32x4){0.f, 0.f, 0.f, 0.f};

#pragma unroll
        for (int ki = 0; ki < 4; ++ki)
#pragma unroll
            for (int nf = 0; nf < 2; ++nf) {
                int sr = nf * 16 + (lane & 15);
                int slot = ki * 4 + (lane >> 4);
                int lofs = sr * 128 + ((slot ^ (sr & 15)) << 3);
                short8 bh = *(short8*)&SH[cur][lofs];
                short8 bl = *(short8*)&SL[cur][lofs];
#pragma unroll
                for (int rg = 0; rg < 2; ++rg) {
                    acc[rg][nf] = __builtin_amdgcn_mfma_f32_16x16x32_bf16(qh[rg][ki], bh, acc[rg][nf], 0, 0, 0);
                    acc[rg][nf] = __builtin_amdgcn_mfma_f32_16x16x32_bf16(qh[rg][ki], bl, acc[rg][nf], 0, 0, 0);
                    acc[rg][nf] = __builtin_amdgcn_mfma_f32_16x16x32_bf16(ql[rg][ki], bh, acc[rg][nf], 0, 0, 0);
                }
            }

#pragma unroll
        for (int nf = 0; nf < 2; ++nf) {
            int s = u * 32 + nf * 16 + (lane & 15);
            if (s < S_) {
                float val = 0.f;
#pragma unroll
                for (int rg = 0; rg < 2; ++rg)
#pragma unroll
                    for (int r = 0; r < 4; ++r)
                        val += fexp2(acc[rg][nf][r]) * invZ[rg][r];
                atomicAdd(&tmps_l[s], val);
            }
        }
        cur ^= 1;
    }
#undef SC_ISSUE0
#undef SC_ISSUE2

    __syncthreads();
    for (int i = t; i < S_; i += 256)
        atomicAdd(&tmps[(size_t)bh_i * S_ + i], tmps_l[i]);
}

// ---------------------------------------------------------------------------
// Top-k (k=10) per (b,h); ties -> smaller index (matches jax.lax.top_k).
// ---------------------------------------------------------------------------
__global__ __launch_bounds__(256) void topk_kernel(
    const float* __restrict__ tmps, int* __restrict__ idxs)
{
    const int bh = blockIdx.x;
    const int t  = threadIdx.x;
    __shared__ float v[S_];
    __shared__ float rv[256];
    __shared__ int   ri[256];

    for (int i = t; i < S_; i += 256) v[i] = tmps[(size_t)bh * S_ + i];
    __syncthreads();

    for (int it = 0; it < TOPK_; ++it) {
        float best = -1e38f;
        int bi = 0x7fffffff;
        for (int s = t; s < S_; s += 256) {
            const float x = v[s];
            if (x > best) { best = x; bi = s; }
        }
        rv[t] = best; ri[t] = bi;
        __syncthreads();
        for (int k = 128; k > 0; k >>= 1) {
            if (t < k) {
                const float x = rv[t + k];
                const int  xi = ri[t + k];
                if (x > rv[t] || (x == rv[t] && xi < ri[t])) { rv[t] = x; ri[t] = xi; }
            }
            __syncthreads();
        }
        if (t == 0) {
            idxs[bh * TOPK_ + it] = ri[0];
            v[ri[0]] = -1e38f;
        }
        __syncthreads();
    }
}

// ---------------------------------------------------------------------------
// Gather selected K rows into tok[b][topk][D]
// ---------------------------------------------------------------------------
__global__ __launch_bounds__(256) void gather_kernel(
    const float* __restrict__ K, const int* __restrict__ idxs,
    float* __restrict__ tok)
{
    const int o = blockIdx.x * 256 + threadIdx.x;
    if (o >= B_ * TOPK_ * D_) return;
    const int d  = o & (D_ - 1);
    const int tt = (o >> 10) % TOPK_;
    const int b  = o / (D_ * TOPK_);
    const int h  = d >> 7;
    const int s  = idxs[(b * H_ + h) * TOPK_ + tt];
    tok[o] = K[(size_t)s * D_ + d];
}

// ---------------------------------------------------------------------------
extern "C" void kernel_launch(void* const* d_in, const int* in_sizes, int n_in,
                              void* d_out, int out_size, void* d_ws, size_t ws_size,
                              hipStream_t stream)
{
    const float* tgt = (const float*)d_in[0];
    const float* src = (const float*)d_in[1];
    const float* Wq  = (const float*)d_in[2];
    const float* bq  = (const float*)d_in[3];
    const float* Wk  = (const float*)d_in[4];
    const float* bk  = (const float*)d_in[5];
    const float* Wo  = (const float*)d_in[6];
    const float* bo  = (const float*)d_in[7];
    float* out = (float*)d_out;

    // workspace layout (bytes, all 256-aligned)
    char* ws = (char*)d_ws;
    size_t off = 0;
    float*          Kbuf = (float*)(ws + off);          off += (size_t)S_ * D_ * 4;
    float*          tmps = (float*)(ws + off);          off += (size_t)B_ * H_ * S_ * 4;
    int*            idxs = (int*)(ws + off);            off += (size_t)B_ * H_ * TOPK_ * 4;
    off = (off + 255) & ~(size_t)255;
    float*          tok  = (float*)(ws + off);          off += (size_t)B_ * TOPK_ * D_ * 4;
    unsigned short* Kh   = (unsigned short*)(ws + off); off += (size_t)1024 * D_ * 2;
    unsigned short* Kl   = (unsigned short*)(ws + off); off += (size_t)1024 * D_ * 2;
    unsigned short* WqTh = (unsigned short*)(ws + off); off += (size_t)D_ * D_ * 2;
    unsigned short* WqTl = (unsigned short*)(ws + off); off += (size_t)D_ * D_ * 2;
    unsigned short* WkTh = (unsigned short*)(ws + off); off += (size_t)D_ * D_ * 2;
    unsigned short* WkTl = (unsigned short*)(ws + off); off += (size_t)D_ * D_ * 2;
    unsigned short* Sh   = (unsigned short*)(ws + off); off += (size_t)1024 * D_ * 2;
    unsigned short* Sl   = (unsigned short*)(ws + off); off += (size_t)1024 * D_ * 2;
    unsigned short* planes = (unsigned short*)(ws + off);
    const size_t fixed_bytes = off;
    const size_t plane_elems_per_b = (size_t)L_ * D_;   // bf16 plane per batch
    // per batch: qh + ql = 2 planes x 4 MB = 8 MB

    int nb_fit = 1;
    if (ws_size > fixed_bytes) {
        size_t f = (ws_size - fixed_bytes) / (2 * plane_elems_per_b * 2);
        nb_fit = (f < 1) ? 1 : (f > 8 ? 8 : (int)f);
    }

    hipMemsetAsync(tmps, 0, (size_t)B_ * H_ * S_ * sizeof(float), stream);

    split_src_kernel<<<(1024 * D_) / (256 * 4), 256, 0, stream>>>(src, Sh, Sl);
    {
        dim3 g(D_ / 64, D_ / 64);
        splitWT_kernel<<<g, 256, 0, stream>>>(Wq, WqTh, WqTl);
        splitWT_kernel<<<g, 256, 0, stream>>>(Wk, WkTh, WkTl);
    }

    // K = src @ Wk + bk via 3-term MFMA (writes Kbuf f32 + Kh/Kl bf16)
    kproj_kernel<<<64, 256, 0, stream>>>(Sh, Sl, WkTh, WkTl, bk, Kbuf, Kh, Kl);

    for (int b0 = 0; b0 < B_; b0 += nb_fit) {
        int nb = (B_ - b0 < nb_fit) ? (B_ - b0) : nb_fit;
        unsigned short* qhb = planes;
        unsigned short* qlb = qhb + (size_t)nb_fit * plane_elems_per_b;

        qproj_kernel<<<nb * 128, 256, 0, stream>>>(
            tgt + (size_t)b0 * L_ * D_, WqTh, WqTl, bq, qhb, qlb);
        scores2p_kernel<<<nb * 128, 256, 0, stream>>>(qhb, qlb, Kh, Kl, tmps, b0);
    }

    topk_kernel<<<B_ * H_, 256, 0, stream>>>(tmps, idxs);
    gather_kernel<<<(B_ * TOPK_ * D_ + 255) / 256, 256, 0, stream>>>(Kbuf, idxs, tok);
    {
        dim3 g(D_ / 64, (B_ * TOPK_ + 63) / 64);
        gemm_bias_kernel<<<g, 256, 0, stream>>>(tok, Wo, bo, out, B_ * TOPK_, D_, D_);
    }
}

// Round 12
// 404.937 us; speedup vs baseline: 1.1219x; 1.0904x over previous
//
#include <hip/hip_runtime.h>
#include <hip/hip_bf16.h>
#include <math.h>

// Problem constants
constexpr int B_ = 8;
constexpr int L_ = 2048;
constexpr int S_ = 1000;
constexpr int D_ = 1024;
constexpr int H_ = 8;
constexpr int E_ = 128;     // D/H
constexpr int TOPK_ = 10;
// (1/sqrt(E)) * log2(e): scores in log2 domain so p = exp2(sc)
constexpr float SCALE_LOG2E_ = 0.12751744f;

typedef __attribute__((ext_vector_type(8))) short short8;   // 8 x bf16 (4 VGPRs)
typedef __attribute__((ext_vector_type(4))) float f32x4;

__device__ inline unsigned short f2bf(float x) {            // RTN-even f32->bf16
    unsigned u = __float_as_uint(x);
    unsigned r = (u + 0x7fffu + ((u >> 16) & 1u)) >> 16;
    return (unsigned short)r;
}
__device__ inline float bf2f(unsigned short s) {
    return __uint_as_float(((unsigned)s) << 16);
}

// fast 2^x (raw v_exp_f32; inputs are |x| < 60 here)
__device__ __forceinline__ float fexp2(float x) {
#if __has_builtin(__builtin_amdgcn_exp2f)
    return __builtin_amdgcn_exp2f(x);
#else
    return __expf(x * 0.69314718056f);
#endif
}

// global -> LDS direct DMA, 16 bytes per lane (m97/m173 pattern).
// LDS dest is linear (wave-uniform base + lane*16); swizzle comes from
// pre-swizzling the per-lane GLOBAL address (bijective per row).
typedef __attribute__((address_space(1))) const unsigned int gas_u32;
typedef __attribute__((address_space(3))) unsigned int las_u32;
__device__ __forceinline__ void gload_lds16(const void* g, void* l) {
    __builtin_amdgcn_global_load_lds((gas_u32*)g, (las_u32*)l, 16, 0, 0);
}

// ---------------------------------------------------------------------------
// Generic f32 GEMM + bias (used only for the tiny 80x1024 output GEMM)
// ---------------------------------------------------------------------------
__global__ __launch_bounds__(256) void gemm_bias_kernel(
    const float* __restrict__ A, const float* __restrict__ Bm,
    const float* __restrict__ bias, float* __restrict__ C,
    int M, int N, int Kd)
{
    __shared__ float As[16][65];
    __shared__ float Bs[16][68];

    const int t  = threadIdx.x;
    const int tx = t & 15;
    const int ty = t >> 4;
    const int m0 = blockIdx.y * 64;
    const int n0 = blockIdx.x * 64;

    float acc[4][4];
#pragma unroll
    for (int i = 0; i < 4; ++i)
#pragma unroll
        for (int j = 0; j < 4; ++j) acc[i][j] = 0.f;

    for (int k0 = 0; k0 < Kd; k0 += 16) {
        {
            const int row = t >> 2;
            const int c4  = (t & 3) * 4;
            float4 v = {0.f, 0.f, 0.f, 0.f};
            if (m0 + row < M)
                v = *(const float4*)&A[(size_t)(m0 + row) * Kd + k0 + c4];
            As[c4 + 0][row] = v.x;
            As[c4 + 1][row] = v.y;
            As[c4 + 2][row] = v.z;
            As[c4 + 3][row] = v.w;
        }
        {
            const int row = t >> 4;
            const int c4  = (t & 15) * 4;
            float4 v = *(const float4*)&Bm[(size_t)(k0 + row) * N + n0 + c4];
            *(float4*)&Bs[row][c4] = v;
        }
        __syncthreads();
#pragma unroll
        for (int k = 0; k < 16; ++k) {
            float a[4], b[4];
#pragma unroll
            for (int i = 0; i < 4; ++i) a[i] = As[k][ty * 4 + i];
            float4 bv = *(const float4*)&Bs[k][tx * 4];
            b[0] = bv.x; b[1] = bv.y; b[2] = bv.z; b[3] = bv.w;
#pragma unroll
            for (int i = 0; i < 4; ++i)
#pragma unroll
                for (int j = 0; j < 4; ++j) acc[i][j] += a[i] * b[j];
        }
        __syncthreads();
    }

#pragma unroll
    for (int i = 0; i < 4; ++i) {
        const int row = m0 + ty * 4 + i;
        if (row < M) {
#pragma unroll
            for (int j = 0; j < 4; ++j) {
                const int col = n0 + tx * 4 + j;
                C[(size_t)row * N + col] = acc[i][j] + bias[col];
            }
        }
    }
}

// ---------------------------------------------------------------------------
// WT split (transpose + hi/lo): WTh/WTl[n][k] = split(W[k][n]). (r2-proven)
// ---------------------------------------------------------------------------
__global__ __launch_bounds__(256) void splitWT_kernel(
    const float* __restrict__ W,
    unsigned short* __restrict__ WTh, unsigned short* __restrict__ WTl)
{
    __shared__ __attribute__((aligned(16))) float tile[64][68];
    const int t  = threadIdx.x;
    const int k0 = blockIdx.y * 64, n0 = blockIdx.x * 64;
#pragma unroll
    for (int it = 0; it < 4; ++it) {
        int id = it * 256 + t;
        int r = id >> 4, c = id & 15;
        *(float4*)&tile[r][c * 4] = *(const float4*)&W[(size_t)(k0 + r) * D_ + n0 + c * 4];
    }
    __syncthreads();
#pragma unroll
    for (int it = 0; it < 4; ++it) {
        int id = it * 256 + t;
        int n = id >> 4, c = id & 15;
        unsigned short hs[4], ls[4];
#pragma unroll
        for (int i = 0; i < 4; ++i) {
            float x = tile[c * 4 + i][n];
            hs[i] = f2bf(x);
            ls[i] = f2bf(x - bf2f(hs[i]));
        }
        size_t o = (size_t)(n0 + n) * D_ + k0 + c * 4;
        uint2 uh; uh.x = (unsigned)hs[0] | ((unsigned)hs[1] << 16);
                  uh.y = (unsigned)hs[2] | ((unsigned)hs[3] << 16);
        uint2 ul; ul.x = (unsigned)ls[0] | ((unsigned)ls[1] << 16);
                  ul.y = (unsigned)ls[2] | ((unsigned)ls[3] << 16);
        *(uint2*)&WTh[o] = uh;
        *(uint2*)&WTl[o] = ul;
    }
}

// ---------------------------------------------------------------------------
// src split: Sh/Sl[1024(pad)][1024] bf16 hi/lo; rows >= 1000 zeroed.
// ---------------------------------------------------------------------------
__global__ __launch_bounds__(256) void split_src_kernel(
    const float* __restrict__ src,
    unsigned short* __restrict__ Sh, unsigned short* __restrict__ Sl)
{
    int idx  = blockIdx.x * 256 + threadIdx.x;
    int base = idx * 4;
    int row  = base >> 10;
    float4 v = {0.f, 0.f, 0.f, 0.f};
    if (row < S_) v = *(const float4*)&src[base];
    float xs[4] = {v.x, v.y, v.z, v.w};
    unsigned short hs[4], ls[4];
#pragma unroll
    for (int i = 0; i < 4; ++i) {
        hs[i] = f2bf(xs[i]);
        ls[i] = f2bf(xs[i] - bf2f(hs[i]));
    }
    uint2 uh; uh.x = (unsigned)hs[0] | ((unsigned)hs[1] << 16);
              uh.y = (unsigned)hs[2] | ((unsigned)hs[3] << 16);
    uint2 ul; ul.x = (unsigned)ls[0] | ((unsigned)ls[1] << 16);
              ul.y = (unsigned)ls[2] | ((unsigned)ls[3] << 16);
    *(uint2*)&Sh[base] = uh;
    *(uint2*)&Sl[base] = ul;
}

// ---------------------------------------------------------------------------
// K projection via 3-term split-bf16 MFMA (r7/r8-proven, all-DMA staging).
// Writes Kbuf (f32, path to output) AND Kh/Kl (hi/lo, pad rows zero).
// ---------------------------------------------------------------------------
__global__ __launch_bounds__(256, 2) void kproj_kernel(
    const unsigned short* __restrict__ Sh, const unsigned short* __restrict__ Sl,
    const unsigned short* __restrict__ WkTh, const unsigned short* __restrict__ WkTl,
    const float* __restrict__ bk,
    float* __restrict__ Kbuf,
    unsigned short* __restrict__ Kh, unsigned short* __restrict__ Kl)
{
    __shared__ __attribute__((aligned(16))) unsigned short Ah[128 * 64];
    __shared__ __attribute__((aligned(16))) unsigned short Al[128 * 64];
    __shared__ __attribute__((aligned(16))) unsigned short Bh[128 * 64];
    __shared__ __attribute__((aligned(16))) unsigned short Bl[128 * 64];

    const int t    = threadIdx.x;
    const int lane = t & 63, w = t >> 6;
    const int mb   = blockIdx.x >> 3;
    const int n0   = (blockIdx.x & 7) * 128;

    f32x4 acc[2][8];
#pragma unroll
    for (int m = 0; m < 2; ++m)
#pragma unroll
        for (int n = 0; n < 8; ++n) acc[m][n] = (f32x4){0.f, 0.f, 0.f, 0.f};

    for (int k0 = 0; k0 < D_; k0 += 64) {
        __syncthreads();
#pragma unroll
        for (int it = 0; it < 4; ++it) {   // DMA all 4 planes, swizzled src
            int r = it * 32 + (t >> 3), c = t & 7;
            size_t gofs = (size_t)r * D_ + k0 + ((c ^ (r & 7)) << 3);
            int db = it * 4096 + t * 16;
            gload_lds16(&Sh[(size_t)(mb * 128) * D_ + gofs], (char*)Ah + db);
            gload_lds16(&Sl[(size_t)(mb * 128) * D_ + gofs], (char*)Al + db);
            gload_lds16(&WkTh[(size_t)n0 * D_ + gofs], (char*)Bh + db);
            gload_lds16(&WkTl[(size_t)n0 * D_ + gofs], (char*)Bl + db);
        }
        __syncthreads();

#pragma unroll
        for (int ki = 0; ki < 2; ++ki) {
            short8 ah[2], al[2];
#pragma unroll
            for (int m = 0; m < 2; ++m) {
                int r = w * 32 + m * 16 + (lane & 15);
                int slot = ki * 4 + (lane >> 4);
                int lofs = r * 64 + ((slot ^ (r & 7)) << 3);
                ah[m] = *(short8*)&Ah[lofs];
                al[m] = *(short8*)&Al[lofs];
            }
#pragma unroll
            for (int n = 0; n < 8; ++n) {
                int nn = n * 16 + (lane & 15);
                int slot = ki * 4 + (lane >> 4);
                int lofs = nn * 64 + ((slot ^ (nn & 7)) << 3);
                short8 bh = *(short8*)&Bh[lofs];
                short8 bl = *(short8*)&Bl[lofs];
#pragma unroll
                for (int m = 0; m < 2; ++m) {
                    acc[m][n] = __builtin_amdgcn_mfma_f32_16x16x32_bf16(ah[m], bh, acc[m][n], 0, 0, 0);
                    acc[m][n] = __builtin_amdgcn_mfma_f32_16x16x32_bf16(ah[m], bl, acc[m][n], 0, 0, 0);
                    acc[m][n] = __builtin_amdgcn_mfma_f32_16x16x32_bf16(al[m], bh, acc[m][n], 0, 0, 0);
                }
            }
        }
    }

#pragma unroll
    for (int n = 0; n < 8; ++n) {
        int col = n0 + n * 16 + (lane & 15);
        float bkv = bk[col];
#pragma unroll
        for (int m = 0; m < 2; ++m) {
            int rbase = mb * 128 + w * 32 + m * 16 + ((lane >> 4) << 2);
#pragma unroll
            for (int r = 0; r < 4; ++r) {
                int row = rbase + r;
                unsigned short hh = 0, ll = 0;
                if (row < S_) {
                    float kv = acc[m][n][r] + bkv;
                    Kbuf[(size_t)row * D_ + col] = kv;
                    hh = f2bf(kv);
                    ll = f2bf(kv - bf2f(hh));
                }
                Kh[(size_t)row * D_ + col] = hh;
                Kl[(size_t)row * D_ + col] = ll;
            }
        }
    }
}

// ---------------------------------------------------------------------------
// Q projection v4 (r9-proven): A staged raw f32 via DMA, f32->hi/lo at
// fragment-read time; B via DMA. BK=32, dbuf, one barrier per tile.
// ---------------------------------------------------------------------------
__global__ __launch_bounds__(256, 2) void qproj_kernel(
    const float* __restrict__ tgt,   // pre-offset to chunk start
    const unsigned short* __restrict__ WqTh, const unsigned short* __restrict__ WqTl,
    const float* __restrict__ bq,
    unsigned short* __restrict__ qhb, unsigned short* __restrict__ qlb)
{
    __shared__ __attribute__((aligned(16))) float          Af[2][128 * 32];
    __shared__ __attribute__((aligned(16))) unsigned short Bh[2][128 * 32];
    __shared__ __attribute__((aligned(16))) unsigned short Bl[2][128 * 32];

    const int t    = threadIdx.x;
    const int lane = t & 63, w = t >> 6;
    const int mb   = blockIdx.x >> 3;
    const int n0   = (blockIdx.x & 7) * 128;

    f32x4 acc[2][8];
#pragma unroll
    for (int m = 0; m < 2; ++m)
#pragma unroll
        for (int n = 0; n < 8; ++n) acc[m][n] = (f32x4){0.f, 0.f, 0.f, 0.f};

#define QP_ISSUE(KT, BUF)                                                   \
    do {                                                                    \
        _Pragma("unroll")                                                   \
        for (int it = 0; it < 4; ++it) {   /* A: 128 rows x 32 f32 */       \
            int id = it * 256 + t;                                          \
            int r = id >> 3, c = id & 7;   /* c: 16B chunk (4 f32) */       \
            size_t ga = (size_t)(mb * 128 + r) * D_ + (KT) * 32             \
                        + ((c ^ (r & 7)) << 2);                             \
            gload_lds16(&tgt[ga], (char*)&Af[(BUF)][0] + it * 4096 + t * 16); \
        }                                                                   \
        _Pragma("unroll")                                                   \
        for (int it = 0; it < 2; ++it) {   /* B: 128 rows x 32 bf16 x2 */   \
            int id = it * 256 + t;                                          \
            int r = id >> 2, c = id & 3;   /* c: 16B chunk (8 bf16) */      \
            size_t gb = (size_t)(n0 + r) * D_ + (KT) * 32                   \
                        + ((c ^ (r & 3)) << 3);                             \
            int db = it * 4096 + t * 16;                                    \
            gload_lds16(&WqTh[gb], (char*)&Bh[(BUF)][0] + db);              \
            gload_lds16(&WqTl[gb], (char*)&Bl[(BUF)][0] + db);              \
        }                                                                   \
    } while (0)

    QP_ISSUE(0, 0);
    int cur = 0;
    for (int kt = 0; kt < 32; ++kt) {
        __syncthreads();              // buf[cur] DMA drained; prior reads done
        if (kt < 31) QP_ISSUE(kt + 1, cur ^ 1);

        // A frags: read f32, convert to hi/lo in registers
        short8 ah[2], al[2];
#pragma unroll
        for (int m = 0; m < 2; ++m) {
            int r  = w * 32 + m * 16 + (lane & 15);
            int c0 = (lane >> 4) * 2;
            float4 x0 = *(float4*)&Af[cur][r * 32 + ((c0 ^ (r & 7)) << 2)];
            float4 x1 = *(float4*)&Af[cur][r * 32 + (((c0 + 1) ^ (r & 7)) << 2)];
            float xs[8] = {x0.x, x0.y, x0.z, x0.w, x1.x, x1.y, x1.z, x1.w};
#pragma unroll
            for (int j = 0; j < 8; ++j) {
                unsigned short hh = f2bf(xs[j]);
                ah[m][j] = (short)hh;
                al[m][j] = (short)f2bf(xs[j] - bf2f(hh));
            }
        }
#pragma unroll
        for (int n = 0; n < 8; ++n) {
            int nn = n * 16 + (lane & 15);
            int lofs = nn * 32 + (((lane >> 4) ^ (nn & 3)) << 3);
            short8 bh = *(short8*)&Bh[cur][lofs];
            short8 bl = *(short8*)&Bl[cur][lofs];
#pragma unroll
            for (int m = 0; m < 2; ++m) {
                acc[m][n] = __builtin_amdgcn_mfma_f32_16x16x32_bf16(ah[m], bh, acc[m][n], 0, 0, 0);
                acc[m][n] = __builtin_amdgcn_mfma_f32_16x16x32_bf16(ah[m], bl, acc[m][n], 0, 0, 0);
                acc[m][n] = __builtin_amdgcn_mfma_f32_16x16x32_bf16(al[m], bh, acc[m][n], 0, 0, 0);
            }
        }
        cur ^= 1;
    }
#undef QP_ISSUE

#pragma unroll
    for (int n = 0; n < 8; ++n) {
        int col = n0 + n * 16 + (lane & 15);
        float bqv = bq[col];
#pragma unroll
        for (int m = 0; m < 2; ++m) {
            int rbase = mb * 128 + w * 32 + m * 16 + ((lane >> 4) << 2);
#pragma unroll
            for (int r = 0; r < 4; ++r) {
                float q = (acc[m][n][r] + bqv) * SCALE_LOG2E_;
                unsigned short hh = f2bf(q);
                qhb[(size_t)(rbase + r) * D_ + col] = hh;
                qlb[(size_t)(rbase + r) * D_ + col] = f2bf(q - bf2f(hh));
            }
        }
    }
}

// ---------------------------------------------------------------------------
// Scores v5: r9-proven sync structure (one __syncthreads per step, DMA
// double-buffer), 256 q-rows per block (2x MFMA per barrier-drain vs r9).
// Each wave holds 64 q-rows (4 row-groups). Pass 0: Z via 1-term qh*kh on
// 64-row Kh tiles (16 steps). Pass 1: p via 3-term on 32-row Kh+Kl tiles
// (32 steps). Grid: nb * 64 blocks (8 h x 8 l-tiles per batch).
// ---------------------------------------------------------------------------
__global__ __launch_bounds__(256, 2) void scores2p_kernel(
    const unsigned short* __restrict__ qhb, const unsigned short* __restrict__ qlb,
    const unsigned short* __restrict__ Kh, const unsigned short* __restrict__ Kl,
    float* __restrict__ tmps, int b0)
{
    __shared__ __attribute__((aligned(16))) unsigned short SH[2][32 * 128];
    __shared__ __attribute__((aligned(16))) unsigned short SL[2][32 * 128];
    __shared__ float tmps_l[1024];

    const int t    = threadIdx.x;
    const int lane = t & 63, w = t >> 6;
    const int blk  = blockIdx.x;
    const int bb   = blk >> 6;
    const int h    = (blk >> 3) & 7;
    const int lt   = blk & 7;
    const int qrow0 = bb * L_ + lt * 256;        // chunk-local
    const int bh_i  = (b0 + bb) * H_ + h;
    const int kr0   = t >> 4;       // staging: r = it*16 + kr0, chunk c = t&15
    const int kc0   = t & 15;

    for (int i = t; i < 1024; i += 256) tmps_l[i] = 0.f;

    // pass-0 staging: 64-row Kh tile; rows 0-31 -> SH[BUF], 32-63 -> SL[BUF]
#define SC_ISSUE0(ST, BUF)                                                  \
    do {                                                                    \
        _Pragma("unroll")                                                   \
        for (int it = 0; it < 4; ++it) {                                    \
            int r = it * 16 + kr0;                                          \
            size_t g = (size_t)((ST) * 64 + r) * D_ + h * E_                \
                       + ((kc0 ^ (r & 15)) << 3);                           \
            char* base = (it < 2) ? (char*)&SH[(BUF)][0]                    \
                                  : (char*)&SL[(BUF)][0];                   \
            int db = (it & 1) * 4096 + t * 16;                              \
            gload_lds16(&Kh[g], base + db);                                 \
        }                                                                   \
    } while (0)

    // pass-1 staging: 32-row tile, Kh + Kl (4 issues/thread)
#define SC_ISSUE2(ST, BUF)                                                  \
    do {                                                                    \
        _Pragma("unroll")                                                   \
        for (int it = 0; it < 2; ++it) {                                    \
            int r = it * 16 + kr0;                                          \
            size_t g = (size_t)((ST) * 32 + r) * D_ + h * E_                \
                       + ((kc0 ^ (r & 15)) << 3);                           \
            int db = it * 4096 + t * 16;                                    \
            gload_lds16(&Kh[g], (char*)&SH[(BUF)][0] + db);                 \
            gload_lds16(&Kl[g], (char*)&SL[(BUF)][0] + db);                 \
        }                                                                   \
    } while (0)

    SC_ISSUE0(0, 1);                 // tile 0 DMA flies under Q staging

    // ---- stage Q (256 rows x 128 cols, hi/lo) in 8 chunks of 32 rows via
    // SH[0]/SL[0]; wave w owns chunks 2w, 2w+1 (its rows w*64..w*64+63).
    short8 qh[4][4], ql[4][4];
#pragma unroll
    for (int ch = 0; ch < 8; ++ch) {
        __syncthreads();
#pragma unroll
        for (int it = 0; it < 2; ++it) {
            int r = it * 16 + kr0;
            size_t g = (size_t)(qrow0 + ch * 32 + r) * D_ + h * E_ + kc0 * 8;
            int lofs = r * 128 + ((kc0 ^ (r & 15)) << 3);
            *(uint4*)&SH[0][lofs] = *(const uint4*)&qhb[g];
            *(uint4*)&SL[0][lofs] = *(const uint4*)&qlb[g];
        }
        __syncthreads();
        if ((ch >> 1) == w) {
#pragma unroll
            for (int j = 0; j < 2; ++j) {
                int rg = (ch & 1) * 2 + j;
#pragma unroll
                for (int ki = 0; ki < 4; ++ki) {
                    int rq = j * 16 + (lane & 15);
                    int slot = ki * 4 + (lane >> 4);
                    int lofs = rq * 128 + ((slot ^ (rq & 15)) << 3);
                    qh[rg][ki] = *(short8*)&SH[0][lofs];
                    ql[rg][ki] = *(short8*)&SL[0][lofs];
                }
            }
        }
    }

    float zacc[4][4];
#pragma unroll
    for (int rg = 0; rg < 4; ++rg)
#pragma unroll
        for (int r = 0; r < 4; ++r) zacc[rg][r] = 0.f;
    float invZ[4][4];

    int cur = 1;                      // tile 0 landed in buffer 1

    // ============ pass 0: Z via 1-term (qh * kh), 64-row tiles ==========
    for (int u = 0; u < 16; ++u) {
        __syncthreads();              // DMA -> buf[cur] ready
        if (u < 15) SC_ISSUE0(u + 1, cur ^ 1);
        else        SC_ISSUE2(0, cur ^ 1);   // prefetch pass-1 tile 0

        // nf split into halves to cap live accumulators (~32 f32)
#pragma unroll
        for (int nfh = 0; nfh < 2; ++nfh) {
            f32x4 acc[4][2];
#pragma unroll
            for (int rg = 0; rg < 4; ++rg)
#pragma unroll
                for (int n2 = 0; n2 < 2; ++n2) acc[rg][n2] = (f32x4){0.f, 0.f, 0.f, 0.f};

#pragma unroll
            for (int ki = 0; ki < 4; ++ki)
#pragma unroll
                for (int n2 = 0; n2 < 2; ++n2) {
                    int nf = nfh * 2 + n2;
                    int sr = nf * 16 + (lane & 15);       // 0..63
                    int slot = ki * 4 + (lane >> 4);
                    int lofs = (sr & 31) * 128 + ((slot ^ (sr & 15)) << 3);
                    short8 bh = (nf < 2) ? *(short8*)&SH[cur][lofs]
                                         : *(short8*)&SL[cur][lofs];
#pragma unroll
                    for (int rg = 0; rg < 4; ++rg)
                        acc[rg][n2] = __builtin_amdgcn_mfma_f32_16x16x32_bf16(qh[rg][ki], bh, acc[rg][n2], 0, 0, 0);
                }

#pragma unroll
            for (int n2 = 0; n2 < 2; ++n2) {
                int s = u * 64 + (nfh * 2 + n2) * 16 + (lane & 15);
                if (s < S_) {
#pragma unroll
                    for (int rg = 0; rg < 4; ++rg)
#pragma unroll
                        for (int r = 0; r < 4; ++r)
                            zacc[rg][r] += fexp2(acc[rg][n2][r]);
                }
            }
        }

        if (u == 15) {                // Z reduce (wave-local, no barrier)
#pragma unroll
            for (int rg = 0; rg < 4; ++rg)
#pragma unroll
                for (int r = 0; r < 4; ++r) {
                    float z = zacc[rg][r];
                    z += __shfl_xor(z, 1);
                    z += __shfl_xor(z, 2);
                    z += __shfl_xor(z, 4);
                    z += __shfl_xor(z, 8);
                    invZ[rg][r] = 1.f / z;
                }
        }
        cur ^= 1;
    }

    // ================= pass 1: p via 3-term, accumulate tmps ============
    for (int u = 0; u < 32; ++u) {
        __syncthreads();
        if (u < 31) SC_ISSUE2(u + 1, cur ^ 1);

        f32x4 acc[4][2];
#pragma unroll
        for (int rg = 0; rg < 4; ++rg)
#pragma unroll
            for (int nf = 0; nf < 2; ++nf) acc[rg][nf] = (f32x4){0.f, 0.f, 0.f, 0.f};

#pragma unroll
        for (int ki = 0; ki < 4; ++ki)
#pragma unroll
            for (int nf = 0; nf < 2; ++nf) {
                int sr = nf * 16 + (lane & 15);
                int slot = ki * 4 + (lane >> 4);
                int lofs = sr * 128 + ((slot ^ (sr & 15)) << 3);
                short8 bh = *(short8*)&SH[cur][lofs];
                short8 bl = *(short8*)&SL[cur][lofs];
#pragma unroll
                for (int rg = 0; rg < 4; ++rg) {
                    acc[rg][nf] = __builtin_amdgcn_mfma_f32_16x16x32_bf16(qh[rg][ki], bh, acc[rg][nf], 0, 0, 0);
                    acc[rg][nf] = __builtin_amdgcn_mfma_f32_16x16x32_bf16(qh[rg][ki], bl, acc[rg][nf], 0, 0, 0);
                    acc[rg][nf] = __builtin_amdgcn_mfma_f32_16x16x32_bf16(ql[rg][ki], bh, acc[rg][nf], 0, 0, 0);
                }
            }

#pragma unroll
        for (int nf = 0; nf < 2; ++nf) {
            int s = u * 32 + nf * 16 + (lane & 15);
            if (s < S_) {
                float val = 0.f;
#pragma unroll
                for (int rg = 0; rg < 4; ++rg)
#pragma unroll
                    for (int r = 0; r < 4; ++r)
                        val += fexp2(acc[rg][nf][r]) * invZ[rg][r];
                atomicAdd(&tmps_l[s], val);
            }
        }
        cur ^= 1;
    }
#undef SC_ISSUE0
#undef SC_ISSUE2

    __syncthreads();
    for (int i = t; i < S_; i += 256)
        atomicAdd(&tmps[(size_t)bh_i * S_ + i], tmps_l[i]);
}

// ---------------------------------------------------------------------------
// Top-k (k=10) per (b,h); ties -> smaller index (matches jax.lax.top_k).
// ---------------------------------------------------------------------------
__global__ __launch_bounds__(256) void topk_kernel(
    const float* __restrict__ tmps, int* __restrict__ idxs)
{
    const int bh = blockIdx.x;
    const int t  = threadIdx.x;
    __shared__ float v[S_];
    __shared__ float rv[256];
    __shared__ int   ri[256];

    for (int i = t; i < S_; i += 256) v[i] = tmps[(size_t)bh * S_ + i];
    __syncthreads();

    for (int it = 0; it < TOPK_; ++it) {
        float best = -1e38f;
        int bi = 0x7fffffff;
        for (int s = t; s < S_; s += 256) {
            const float x = v[s];
            if (x > best) { best = x; bi = s; }
        }
        rv[t] = best; ri[t] = bi;
        __syncthreads();
        for (int k = 128; k > 0; k >>= 1) {
            if (t < k) {
                const float x = rv[t + k];
                const int  xi = ri[t + k];
                if (x > rv[t] || (x == rv[t] && xi < ri[t])) { rv[t] = x; ri[t] = xi; }
            }
            __syncthreads();
        }
        if (t == 0) {
            idxs[bh * TOPK_ + it] = ri[0];
            v[ri[0]] = -1e38f;
        }
        __syncthreads();
    }
}

// ---------------------------------------------------------------------------
// Gather selected K rows into tok[b][topk][D]
// ---------------------------------------------------------------------------
__global__ __launch_bounds__(256) void gather_kernel(
    const float* __restrict__ K, const int* __restrict__ idxs,
    float* __restrict__ tok)
{
    const int o = blockIdx.x * 256 + threadIdx.x;
    if (o >= B_ * TOPK_ * D_) return;
    const int d  = o & (D_ - 1);
    const int tt = (o >> 10) % TOPK_;
    const int b  = o / (D_ * TOPK_);
    const int h  = d >> 7;
    const int s  = idxs[(b * H_ + h) * TOPK_ + tt];
    tok[o] = K[(size_t)s * D_ + d];
}

// ---------------------------------------------------------------------------
extern "C" void kernel_launch(void* const* d_in, const int* in_sizes, int n_in,
                              void* d_out, int out_size, void* d_ws, size_t ws_size,
                              hipStream_t stream)
{
    const float* tgt = (const float*)d_in[0];
    const float* src = (const float*)d_in[1];
    const float* Wq  = (const float*)d_in[2];
    const float* bq  = (const float*)d_in[3];
    const float* Wk  = (const float*)d_in[4];
    const float* bk  = (const float*)d_in[5];
    const float* Wo  = (const float*)d_in[6];
    const float* bo  = (const float*)d_in[7];
    float* out = (float*)d_out;

    // workspace layout (bytes, all 256-aligned)
    char* ws = (char*)d_ws;
    size_t off = 0;
    float*          Kbuf = (float*)(ws + off);          off += (size_t)S_ * D_ * 4;
    float*          tmps = (float*)(ws + off);          off += (size_t)B_ * H_ * S_ * 4;
    int*            idxs = (int*)(ws + off);            off += (size_t)B_ * H_ * TOPK_ * 4;
    off = (off + 255) & ~(size_t)255;
    float*          tok  = (float*)(ws + off);          off += (size_t)B_ * TOPK_ * D_ * 4;
    unsigned short* Kh   = (unsigned short*)(ws + off); off += (size_t)1024 * D_ * 2;
    unsigned short* Kl   = (unsigned short*)(ws + off); off += (size_t)1024 * D_ * 2;
    unsigned short* WqTh = (unsigned short*)(ws + off); off += (size_t)D_ * D_ * 2;
    unsigned short* WqTl = (unsigned short*)(ws + off); off += (size_t)D_ * D_ * 2;
    unsigned short* WkTh = (unsigned short*)(ws + off); off += (size_t)D_ * D_ * 2;
    unsigned short* WkTl = (unsigned short*)(ws + off); off += (size_t)D_ * D_ * 2;
    unsigned short* Sh   = (unsigned short*)(ws + off); off += (size_t)1024 * D_ * 2;
    unsigned short* Sl   = (unsigned short*)(ws + off); off += (size_t)1024 * D_ * 2;
    unsigned short* planes = (unsigned short*)(ws + off);
    const size_t fixed_bytes = off;
    const size_t plane_elems_per_b = (size_t)L_ * D_;   // bf16 plane per batch
    // per batch: qh + ql = 2 planes x 4 MB = 8 MB

    int nb_fit = 1;
    if (ws_size > fixed_bytes) {
        size_t f = (ws_size - fixed_bytes) / (2 * plane_elems_per_b * 2);
        nb_fit = (f < 1) ? 1 : (f > 8 ? 8 : (int)f);
    }

    hipMemsetAsync(tmps, 0, (size_t)B_ * H_ * S_ * sizeof(float), stream);

    split_src_kernel<<<(1024 * D_) / (256 * 4), 256, 0, stream>>>(src, Sh, Sl);
    {
        dim3 g(D_ / 64, D_ / 64);
        splitWT_kernel<<<g, 256, 0, stream>>>(Wq, WqTh, WqTl);
        splitWT_kernel<<<g, 256, 0, stream>>>(Wk, WkTh, WkTl);
    }

    // K = src @ Wk + bk via 3-term MFMA (writes Kbuf f32 + Kh/Kl bf16)
    kproj_kernel<<<64, 256, 0, stream>>>(Sh, Sl, WkTh, WkTl, bk, Kbuf, Kh, Kl);

    for (int b0 = 0; b0 < B_; b0 += nb_fit) {
        int nb = (B_ - b0 < nb_fit) ? (B_ - b0) : nb_fit;
        unsigned short* qhb = planes;
        unsigned short* qlb = qhb + (size_t)nb_fit * plane_elems_per_b;

        qproj_kernel<<<nb * 128, 256, 0, stream>>>(
            tgt + (size_t)b0 * L_ * D_, WqTh, WqTl, bq, qhb, qlb);
        scores2p_kernel<<<nb * 64, 256, 0, stream>>>(qhb, qlb, Kh, Kl, tmps, b0);
    }

    topk_kernel<<<B_ * H_, 256, 0, stream>>>(tmps, idxs);
    gather_kernel<<<(B_ * TOPK_ * D_ + 255) / 256, 256, 0, stream>>>(Kbuf, idxs, tok);
    {
        dim3 g(D_ / 64, (B_ * TOPK_ + 63) / 64);
        gemm_bias_kernel<<<g, 256, 0, stream>>>(tok, Wo, bo, out, B_ * TOPK_, D_, D_);
    }
}

// Round 13
// 381.771 us; speedup vs baseline: 1.1899x; 1.0607x over previous
//
#include <hip/hip_runtime.h>
#include <hip/hip_bf16.h>
#include <math.h>

// Problem constants
constexpr int B_ = 8;
constexpr int L_ = 2048;
constexpr int S_ = 1000;
constexpr int D_ = 1024;
constexpr int H_ = 8;
constexpr int E_ = 128;     // D/H
constexpr int TOPK_ = 10;
// (1/sqrt(E)) * log2(e): scores in log2 domain so p = exp2(sc)
constexpr float SCALE_LOG2E_ = 0.12751744f;

typedef __attribute__((ext_vector_type(8))) short short8;   // 8 x bf16 (4 VGPRs)
typedef __attribute__((ext_vector_type(4))) float f32x4;

__device__ inline unsigned short f2bf(float x) {            // RTN-even f32->bf16
    unsigned u = __float_as_uint(x);
    unsigned r = (u + 0x7fffu + ((u >> 16) & 1u)) >> 16;
    return (unsigned short)r;
}
__device__ inline float bf2f(unsigned short s) {
    return __uint_as_float(((unsigned)s) << 16);
}

// fast 2^x (raw v_exp_f32; inputs are |x| < 60 here)
__device__ __forceinline__ float fexp2(float x) {
#if __has_builtin(__builtin_amdgcn_exp2f)
    return __builtin_amdgcn_exp2f(x);
#else
    return __expf(x * 0.69314718056f);
#endif
}

// global -> LDS direct DMA, 16 bytes per lane (m97/m173 pattern).
// LDS dest is linear (wave-uniform base + lane*16); swizzle comes from
// pre-swizzling the per-lane GLOBAL address (bijective per line).
typedef __attribute__((address_space(1))) const unsigned int gas_u32;
typedef __attribute__((address_space(3))) unsigned int las_u32;
__device__ __forceinline__ void gload_lds16(const void* g, void* l) {
    __builtin_amdgcn_global_load_lds((gas_u32*)g, (las_u32*)l, 16, 0, 0);
}

// ---------------------------------------------------------------------------
// Generic f32 GEMM + bias (used only for the tiny 80x1024 output GEMM)
// ---------------------------------------------------------------------------
__global__ __launch_bounds__(256) void gemm_bias_kernel(
    const float* __restrict__ A, const float* __restrict__ Bm,
    const float* __restrict__ bias, float* __restrict__ C,
    int M, int N, int Kd)
{
    __shared__ float As[16][65];
    __shared__ float Bs[16][68];

    const int t  = threadIdx.x;
    const int tx = t & 15;
    const int ty = t >> 4;
    const int m0 = blockIdx.y * 64;
    const int n0 = blockIdx.x * 64;

    float acc[4][4];
#pragma unroll
    for (int i = 0; i < 4; ++i)
#pragma unroll
        for (int j = 0; j < 4; ++j) acc[i][j] = 0.f;

    for (int k0 = 0; k0 < Kd; k0 += 16) {
        {
            const int row = t >> 2;
            const int c4  = (t & 3) * 4;
            float4 v = {0.f, 0.f, 0.f, 0.f};
            if (m0 + row < M)
                v = *(const float4*)&A[(size_t)(m0 + row) * Kd + k0 + c4];
            As[c4 + 0][row] = v.x;
            As[c4 + 1][row] = v.y;
            As[c4 + 2][row] = v.z;
            As[c4 + 3][row] = v.w;
        }
        {
            const int row = t >> 4;
            const int c4  = (t & 15) * 4;
            float4 v = *(const float4*)&Bm[(size_t)(k0 + row) * N + n0 + c4];
            *(float4*)&Bs[row][c4] = v;
        }
        __syncthreads();
#pragma unroll
        for (int k = 0; k < 16; ++k) {
            float a[4], b[4];
#pragma unroll
            for (int i = 0; i < 4; ++i) a[i] = As[k][ty * 4 + i];
            float4 bv = *(const float4*)&Bs[k][tx * 4];
            b[0] = bv.x; b[1] = bv.y; b[2] = bv.z; b[3] = bv.w;
#pragma unroll
            for (int i = 0; i < 4; ++i)
#pragma unroll
                for (int j = 0; j < 4; ++j) acc[i][j] += a[i] * b[j];
        }
        __syncthreads();
    }

#pragma unroll
    for (int i = 0; i < 4; ++i) {
        const int row = m0 + ty * 4 + i;
        if (row < M) {
#pragma unroll
            for (int j = 0; j < 4; ++j) {
                const int col = n0 + tx * 4 + j;
                C[(size_t)row * N + col] = acc[i][j] + bias[col];
            }
        }
    }
}

// ---------------------------------------------------------------------------
// WT split (transpose + hi/lo): WTh/WTl[n][k] = split(W[k][n]). (r2-proven)
// ---------------------------------------------------------------------------
__global__ __launch_bounds__(256) void splitWT_kernel(
    const float* __restrict__ W,
    unsigned short* __restrict__ WTh, unsigned short* __restrict__ WTl)
{
    __shared__ __attribute__((aligned(16))) float tile[64][68];
    const int t  = threadIdx.x;
    const int k0 = blockIdx.y * 64, n0 = blockIdx.x * 64;
#pragma unroll
    for (int it = 0; it < 4; ++it) {
        int id = it * 256 + t;
        int r = id >> 4, c = id & 15;
        *(float4*)&tile[r][c * 4] = *(const float4*)&W[(size_t)(k0 + r) * D_ + n0 + c * 4];
    }
    __syncthreads();
#pragma unroll
    for (int it = 0; it < 4; ++it) {
        int id = it * 256 + t;
        int n = id >> 4, c = id & 15;
        unsigned short hs[4], ls[4];
#pragma unroll
        for (int i = 0; i < 4; ++i) {
            float x = tile[c * 4 + i][n];
            hs[i] = f2bf(x);
            ls[i] = f2bf(x - bf2f(hs[i]));
        }
        size_t o = (size_t)(n0 + n) * D_ + k0 + c * 4;
        uint2 uh; uh.x = (unsigned)hs[0] | ((unsigned)hs[1] << 16);
                  uh.y = (unsigned)hs[2] | ((unsigned)hs[3] << 16);
        uint2 ul; ul.x = (unsigned)ls[0] | ((unsigned)ls[1] << 16);
                  ul.y = (unsigned)ls[2] | ((unsigned)ls[3] << 16);
        *(uint2*)&WTh[o] = uh;
        *(uint2*)&WTl[o] = ul;
    }
}

// ---------------------------------------------------------------------------
// src split: Sh/Sl[1024(pad)][1024] bf16 hi/lo; rows >= 1000 zeroed.
// ---------------------------------------------------------------------------
__global__ __launch_bounds__(256) void split_src_kernel(
    const float* __restrict__ src,
    unsigned short* __restrict__ Sh, unsigned short* __restrict__ Sl)
{
    int idx  = blockIdx.x * 256 + threadIdx.x;
    int base = idx * 4;
    int row  = base >> 10;
    float4 v = {0.f, 0.f, 0.f, 0.f};
    if (row < S_) v = *(const float4*)&src[base];
    float xs[4] = {v.x, v.y, v.z, v.w};
    unsigned short hs[4], ls[4];
#pragma unroll
    for (int i = 0; i < 4; ++i) {
        hs[i] = f2bf(xs[i]);
        ls[i] = f2bf(xs[i] - bf2f(hs[i]));
    }
    uint2 uh; uh.x = (unsigned)hs[0] | ((unsigned)hs[1] << 16);
              uh.y = (unsigned)hs[2] | ((unsigned)hs[3] << 16);
    uint2 ul; ul.x = (unsigned)ls[0] | ((unsigned)ls[1] << 16);
              ul.y = (unsigned)ls[2] | ((unsigned)ls[3] << 16);
    *(uint2*)&Sh[base] = uh;
    *(uint2*)&Sl[base] = ul;
}

// ---------------------------------------------------------------------------
// K projection via 3-term split-bf16 MFMA (r7/r8-proven, all-DMA staging).
// Writes Kbuf (f32, path to output) AND Kh/Kl (hi/lo, pad rows zero).
// ---------------------------------------------------------------------------
__global__ __launch_bounds__(256, 2) void kproj_kernel(
    const unsigned short* __restrict__ Sh, const unsigned short* __restrict__ Sl,
    const unsigned short* __restrict__ WkTh, const unsigned short* __restrict__ WkTl,
    const float* __restrict__ bk,
    float* __restrict__ Kbuf,
    unsigned short* __restrict__ Kh, unsigned short* __restrict__ Kl)
{
    __shared__ __attribute__((aligned(16))) unsigned short Ah[128 * 64];
    __shared__ __attribute__((aligned(16))) unsigned short Al[128 * 64];
    __shared__ __attribute__((aligned(16))) unsigned short Bh[128 * 64];
    __shared__ __attribute__((aligned(16))) unsigned short Bl[128 * 64];

    const int t    = threadIdx.x;
    const int lane = t & 63, w = t >> 6;
    const int mb   = blockIdx.x >> 3;
    const int n0   = (blockIdx.x & 7) * 128;

    f32x4 acc[2][8];
#pragma unroll
    for (int m = 0; m < 2; ++m)
#pragma unroll
        for (int n = 0; n < 8; ++n) acc[m][n] = (f32x4){0.f, 0.f, 0.f, 0.f};

    for (int k0 = 0; k0 < D_; k0 += 64) {
        __syncthreads();
#pragma unroll
        for (int it = 0; it < 4; ++it) {   // DMA all 4 planes, swizzled src
            int r = it * 32 + (t >> 3), c = t & 7;
            size_t gofs = (size_t)r * D_ + k0 + ((c ^ (r & 7)) << 3);
            int db = it * 4096 + t * 16;
            gload_lds16(&Sh[(size_t)(mb * 128) * D_ + gofs], (char*)Ah + db);
            gload_lds16(&Sl[(size_t)(mb * 128) * D_ + gofs], (char*)Al + db);
            gload_lds16(&WkTh[(size_t)n0 * D_ + gofs], (char*)Bh + db);
            gload_lds16(&WkTl[(size_t)n0 * D_ + gofs], (char*)Bl + db);
        }
        __syncthreads();

#pragma unroll
        for (int ki = 0; ki < 2; ++ki) {
            short8 ah[2], al[2];
#pragma unroll
            for (int m = 0; m < 2; ++m) {
                int r = w * 32 + m * 16 + (lane & 15);
                int slot = ki * 4 + (lane >> 4);
                int lofs = r * 64 + ((slot ^ (r & 7)) << 3);
                ah[m] = *(short8*)&Ah[lofs];
                al[m] = *(short8*)&Al[lofs];
            }
#pragma unroll
            for (int n = 0; n < 8; ++n) {
                int nn = n * 16 + (lane & 15);
                int slot = ki * 4 + (lane >> 4);
                int lofs = nn * 64 + ((slot ^ (nn & 7)) << 3);
                short8 bh = *(short8*)&Bh[lofs];
                short8 bl = *(short8*)&Bl[lofs];
#pragma unroll
                for (int m = 0; m < 2; ++m) {
                    acc[m][n] = __builtin_amdgcn_mfma_f32_16x16x32_bf16(ah[m], bh, acc[m][n], 0, 0, 0);
                    acc[m][n] = __builtin_amdgcn_mfma_f32_16x16x32_bf16(ah[m], bl, acc[m][n], 0, 0, 0);
                    acc[m][n] = __builtin_amdgcn_mfma_f32_16x16x32_bf16(al[m], bh, acc[m][n], 0, 0, 0);
                }
            }
        }
    }

#pragma unroll
    for (int n = 0; n < 8; ++n) {
        int col = n0 + n * 16 + (lane & 15);
        float bkv = bk[col];
#pragma unroll
        for (int m = 0; m < 2; ++m) {
            int rbase = mb * 128 + w * 32 + m * 16 + ((lane >> 4) << 2);
#pragma unroll
            for (int r = 0; r < 4; ++r) {
                int row = rbase + r;
                unsigned short hh = 0, ll = 0;
                if (row < S_) {
                    float kv = acc[m][n][r] + bkv;
                    Kbuf[(size_t)row * D_ + col] = kv;
                    hh = f2bf(kv);
                    ll = f2bf(kv - bf2f(hh));
                }
                Kh[(size_t)row * D_ + col] = hh;
                Kl[(size_t)row * D_ + col] = ll;
            }
        }
    }
}

// ---------------------------------------------------------------------------
// Q projection v5: r12 v4 structure + two memory fixes (numerics bitwise
// identical):
//  (1) XCD-grouped block mapping: the 8 n-blocks sharing an mb tgt-tile land
//      on ONE XCD, temporally adjacent -> tile fetched into one L2 once.
//  (2) A/B LDS layouts use 256-B lines with 4-bit XOR (the scores pattern,
//      measured 0 conflicts): A line = 2 rows x 32 f32, B line = 4 rows x
//      32 bf16; sub ^ (line & 15) involution on DMA source AND read.
// ---------------------------------------------------------------------------
__global__ __launch_bounds__(256, 2) void qproj_kernel(
    const float* __restrict__ tgt,   // pre-offset to chunk start
    const unsigned short* __restrict__ WqTh, const unsigned short* __restrict__ WqTl,
    const float* __restrict__ bq,
    unsigned short* __restrict__ qhb, unsigned short* __restrict__ qlb)
{
    __shared__ __attribute__((aligned(16))) float          Af[2][128 * 32];
    __shared__ __attribute__((aligned(16))) unsigned short Bh[2][128 * 32];
    __shared__ __attribute__((aligned(16))) unsigned short Bl[2][128 * 32];

    const int t    = threadIdx.x;
    const int lane = t & 63, w = t >> 6;
    // XCD-grouped mapping (bijective: grid = nb*128, always % 8 == 0)
    const int x    = blockIdx.x & 7;         // XCD slot
    const int jj   = blockIdx.x >> 3;
    const int n0   = (jj & 7) * 128;
    const int mb   = (jj >> 3) * 8 + x;

    f32x4 acc[2][8];
#pragma unroll
    for (int m = 0; m < 2; ++m)
#pragma unroll
        for (int n = 0; n < 8; ++n) acc[m][n] = (f32x4){0.f, 0.f, 0.f, 0.f};

    // A: 1024 granules (128 rows x 32 f32), line = id>>4 (2 rows), sub = id&15
    // B: 512 granules (128 rows x 32 bf16), line = id>>4 (4 rows), sub = id&15
#define QP_ISSUE(KT, BUF)                                                   \
    do {                                                                    \
        _Pragma("unroll")                                                   \
        for (int it = 0; it < 4; ++it) {   /* A plane */                    \
            int id = it * 256 + t;                                          \
            int line = id >> 4, sub = id & 15;                              \
            int gs = sub ^ (line & 15);                                     \
            size_t ga = (size_t)(mb * 128 + line * 2 + (gs >> 3)) * D_      \
                        + (KT) * 32 + ((gs & 7) << 2);                      \
            gload_lds16(&tgt[ga], (char*)&Af[(BUF)][0] + id * 16);          \
        }                                                                   \
        _Pragma("unroll")                                                   \
        for (int it = 0; it < 2; ++it) {   /* B planes */                   \
            int id = it * 256 + t;                                          \
            int line = id >> 4, sub = id & 15;                              \
            int gs = sub ^ (line & 15);                                     \
            size_t gb = (size_t)(n0 + line * 4 + (gs >> 2)) * D_            \
                        + (KT) * 32 + ((gs & 3) << 3);                      \
            gload_lds16(&WqTh[gb], (char*)&Bh[(BUF)][0] + id * 16);         \
            gload_lds16(&WqTl[gb], (char*)&Bl[(BUF)][0] + id * 16);         \
        }                                                                   \
    } while (0)

    QP_ISSUE(0, 0);
    int cur = 0;
    for (int kt = 0; kt < 32; ++kt) {
        __syncthreads();              // buf[cur] DMA drained; prior reads done
        if (kt < 31) QP_ISSUE(kt + 1, cur ^ 1);

        // A frags: read f32 (256-B-line swizzled), convert to hi/lo in regs
        short8 ah[2], al[2];
#pragma unroll
        for (int m = 0; m < 2; ++m) {
            int r    = w * 32 + m * 16 + (lane & 15);
            int c0   = (lane >> 4) * 2;
            int line = r >> 1;
            int sub0 = (r & 1) * 8 + c0;
            float4 x0 = *(float4*)&Af[cur][line * 64 + ((sub0 ^ (line & 15)) << 2)];
            float4 x1 = *(float4*)&Af[cur][line * 64 + (((sub0 + 1) ^ (line & 15)) << 2)];
            float xs[8] = {x0.x, x0.y, x0.z, x0.w, x1.x, x1.y, x1.z, x1.w};
#pragma unroll
            for (int jjj = 0; jjj < 8; ++jjj) {
                unsigned short hh = f2bf(xs[jjj]);
                ah[m][jjj] = (short)hh;
                al[m][jjj] = (short)f2bf(xs[jjj] - bf2f(hh));
            }
        }
#pragma unroll
        for (int n = 0; n < 8; ++n) {
            int nn   = n * 16 + (lane & 15);
            int line = nn >> 2;
            int sub  = (nn & 3) * 4 + (lane >> 4);
            int lofs = line * 128 + ((sub ^ (line & 15)) << 3);
            short8 bh = *(short8*)&Bh[cur][lofs];
            short8 bl = *(short8*)&Bl[cur][lofs];
#pragma unroll
            for (int m = 0; m < 2; ++m) {
                acc[m][n] = __builtin_amdgcn_mfma_f32_16x16x32_bf16(ah[m], bh, acc[m][n], 0, 0, 0);
                acc[m][n] = __builtin_amdgcn_mfma_f32_16x16x32_bf16(ah[m], bl, acc[m][n], 0, 0, 0);
                acc[m][n] = __builtin_amdgcn_mfma_f32_16x16x32_bf16(al[m], bh, acc[m][n], 0, 0, 0);
            }
        }
        cur ^= 1;
    }
#undef QP_ISSUE

#pragma unroll
    for (int n = 0; n < 8; ++n) {
        int col = n0 + n * 16 + (lane & 15);
        float bqv = bq[col];
#pragma unroll
        for (int m = 0; m < 2; ++m) {
            int rbase = mb * 128 + w * 32 + m * 16 + ((lane >> 4) << 2);
#pragma unroll
            for (int r = 0; r < 4; ++r) {
                float q = (acc[m][n][r] + bqv) * SCALE_LOG2E_;
                unsigned short hh = f2bf(q);
                qhb[(size_t)(rbase + r) * D_ + col] = hh;
                qlb[(size_t)(rbase + r) * D_ + col] = f2bf(q - bf2f(hh));
            }
        }
    }
}

// ---------------------------------------------------------------------------
// Scores v5 (r12-proven): 256 q-rows per block, one __syncthreads per step,
// DMA double-buffer. Pass 0: Z via 1-term qh*kh on 64-row Kh tiles.
// Pass 1: p via 3-term on 32-row Kh+Kl tiles. Grid: nb * 64 blocks.
// ---------------------------------------------------------------------------
__global__ __launch_bounds__(256, 2) void scores2p_kernel(
    const unsigned short* __restrict__ qhb, const unsigned short* __restrict__ qlb,
    const unsigned short* __restrict__ Kh, const unsigned short* __restrict__ Kl,
    float* __restrict__ tmps, int b0)
{
    __shared__ __attribute__((aligned(16))) unsigned short SH[2][32 * 128];
    __shared__ __attribute__((aligned(16))) unsigned short SL[2][32 * 128];
    __shared__ float tmps_l[1024];

    const int t    = threadIdx.x;
    const int lane = t & 63, w = t >> 6;
    const int blk  = blockIdx.x;
    const int bb   = blk >> 6;
    const int h    = (blk >> 3) & 7;
    const int lt   = blk & 7;
    const int qrow0 = bb * L_ + lt * 256;        // chunk-local
    const int bh_i  = (b0 + bb) * H_ + h;
    const int kr0   = t >> 4;       // staging: r = it*16 + kr0, chunk c = t&15
    const int kc0   = t & 15;

    for (int i = t; i < 1024; i += 256) tmps_l[i] = 0.f;

    // pass-0 staging: 64-row Kh tile; rows 0-31 -> SH[BUF], 32-63 -> SL[BUF]
#define SC_ISSUE0(ST, BUF)                                                  \
    do {                                                                    \
        _Pragma("unroll")                                                   \
        for (int it = 0; it < 4; ++it) {                                    \
            int r = it * 16 + kr0;                                          \
            size_t g = (size_t)((ST) * 64 + r) * D_ + h * E_                \
                       + ((kc0 ^ (r & 15)) << 3);                           \
            char* base = (it < 2) ? (char*)&SH[(BUF)][0]                    \
                                  : (char*)&SL[(BUF)][0];                   \
            int db = (it & 1) * 4096 + t * 16;                              \
            gload_lds16(&Kh[g], base + db);                                 \
        }                                                                   \
    } while (0)

    // pass-1 staging: 32-row tile, Kh + Kl (4 issues/thread)
#define SC_ISSUE2(ST, BUF)                                                  \
    do {                                                                    \
        _Pragma("unroll")                                                   \
        for (int it = 0; it < 2; ++it) {                                    \
            int r = it * 16 + kr0;                                          \
            size_t g = (size_t)((ST) * 32 + r) * D_ + h * E_                \
                       + ((kc0 ^ (r & 15)) << 3);                           \
            int db = it * 4096 + t * 16;                                    \
            gload_lds16(&Kh[g], (char*)&SH[(BUF)][0] + db);                 \
            gload_lds16(&Kl[g], (char*)&SL[(BUF)][0] + db);                 \
        }                                                                   \
    } while (0)

    SC_ISSUE0(0, 1);                 // tile 0 DMA flies under Q staging

    // ---- stage Q (256 rows x 128 cols, hi/lo) in 8 chunks of 32 rows via
    // SH[0]/SL[0]; wave w owns chunks 2w, 2w+1 (its rows w*64..w*64+63).
    short8 qh[4][4], ql[4][4];
#pragma unroll
    for (int ch = 0; ch < 8; ++ch) {
        __syncthreads();
#pragma unroll
        for (int it = 0; it < 2; ++it) {
            int r = it * 16 + kr0;
            size_t g = (size_t)(qrow0 + ch * 32 + r) * D_ + h * E_ + kc0 * 8;
            int lofs = r * 128 + ((kc0 ^ (r & 15)) << 3);
            *(uint4*)&SH[0][lofs] = *(const uint4*)&qhb[g];
            *(uint4*)&SL[0][lofs] = *(const uint4*)&qlb[g];
        }
        __syncthreads();
        if ((ch >> 1) == w) {
#pragma unroll
            for (int j = 0; j < 2; ++j) {
                int rg = (ch & 1) * 2 + j;
#pragma unroll
                for (int ki = 0; ki < 4; ++ki) {
                    int rq = j * 16 + (lane & 15);
                    int slot = ki * 4 + (lane >> 4);
                    int lofs = rq * 128 + ((slot ^ (rq & 15)) << 3);
                    qh[rg][ki] = *(short8*)&SH[0][lofs];
                    ql[rg][ki] = *(short8*)&SL[0][lofs];
                }
            }
        }
    }

    float zacc[4][4];
#pragma unroll
    for (int rg = 0; rg < 4; ++rg)
#pragma unroll
        for (int r = 0; r < 4; ++r) zacc[rg][r] = 0.f;
    float invZ[4][4];

    int cur = 1;                      // tile 0 landed in buffer 1

    // ============ pass 0: Z via 1-term (qh * kh), 64-row tiles ==========
    for (int u = 0; u < 16; ++u) {
        __syncthreads();              // DMA -> buf[cur] ready
        if (u < 15) SC_ISSUE0(u + 1, cur ^ 1);
        else        SC_ISSUE2(0, cur ^ 1);   // prefetch pass-1 tile 0

        // nf split into halves to cap live accumulators (~32 f32)
#pragma unroll
        for (int nfh = 0; nfh < 2; ++nfh) {
            f32x4 acc[4][2];
#pragma unroll
            for (int rg = 0; rg < 4; ++rg)
#pragma unroll
                for (int n2 = 0; n2 < 2; ++n2) acc[rg][n2] = (f32x4){0.f, 0.f, 0.f, 0.f};

#pragma unroll
            for (int ki = 0; ki < 4; ++ki)
#pragma unroll
                for (int n2 = 0; n2 < 2; ++n2) {
                    int nf = nfh * 2 + n2;
                    int sr = nf * 16 + (lane & 15);       // 0..63
                    int slot = ki * 4 + (lane >> 4);
                    int lofs = (sr & 31) * 128 + ((slot ^ (sr & 15)) << 3);
                    short8 bh = (nf < 2) ? *(short8*)&SH[cur][lofs]
                                         : *(short8*)&SL[cur][lofs];
#pragma unroll
                    for (int rg = 0; rg < 4; ++rg)
                        acc[rg][n2] = __builtin_amdgcn_mfma_f32_16x16x32_bf16(qh[rg][ki], bh, acc[rg][n2], 0, 0, 0);
                }

#pragma unroll
            for (int n2 = 0; n2 < 2; ++n2) {
                int s = u * 64 + (nfh * 2 + n2) * 16 + (lane & 15);
                if (s < S_) {
#pragma unroll
                    for (int rg = 0; rg < 4; ++rg)
#pragma unroll
                        for (int r = 0; r < 4; ++r)
                            zacc[rg][r] += fexp2(acc[rg][n2][r]);
                }
            }
        }

        if (u == 15) {                // Z reduce (wave-local, no barrier)
#pragma unroll
            for (int rg = 0; rg < 4; ++rg)
#pragma unroll
                for (int r = 0; r < 4; ++r) {
                    float z = zacc[rg][r];
                    z += __shfl_xor(z, 1);
                    z += __shfl_xor(z, 2);
                    z += __shfl_xor(z, 4);
                    z += __shfl_xor(z, 8);
                    invZ[rg][r] = 1.f / z;
                }
        }
        cur ^= 1;
    }

    // ================= pass 1: p via 3-term, accumulate tmps ============
    for (int u = 0; u < 32; ++u) {
        __syncthreads();
        if (u < 31) SC_ISSUE2(u + 1, cur ^ 1);

        f32x4 acc[4][2];
#pragma unroll
        for (int rg = 0; rg < 4; ++rg)
#pragma unroll
            for (int nf = 0; nf < 2; ++nf) acc[rg][nf] = (f32x4){0.f, 0.f, 0.f, 0.f};

#pragma unroll
        for (int ki = 0; ki < 4; ++ki)
#pragma unroll
            for (int nf = 0; nf < 2; ++nf) {
                int sr = nf * 16 + (lane & 15);
                int slot = ki * 4 + (lane >> 4);
                int lofs = sr * 128 + ((slot ^ (sr & 15)) << 3);
                short8 bh = *(short8*)&SH[cur][lofs];
                short8 bl = *(short8*)&SL[cur][lofs];
#pragma unroll
                for (int rg = 0; rg < 4; ++rg) {
                    acc[rg][nf] = __builtin_amdgcn_mfma_f32_16x16x32_bf16(qh[rg][ki], bh, acc[rg][nf], 0, 0, 0);
                    acc[rg][nf] = __builtin_amdgcn_mfma_f32_16x16x32_bf16(qh[rg][ki], bl, acc[rg][nf], 0, 0, 0);
                    acc[rg][nf] = __builtin_amdgcn_mfma_f32_16x16x32_bf16(ql[rg][ki], bh, acc[rg][nf], 0, 0, 0);
                }
            }

#pragma unroll
        for (int nf = 0; nf < 2; ++nf) {
            int s = u * 32 + nf * 16 + (lane & 15);
            if (s < S_) {
                float val = 0.f;
#pragma unroll
                for (int rg = 0; rg < 4; ++rg)
#pragma unroll
                    for (int r = 0; r < 4; ++r)
                        val += fexp2(acc[rg][nf][r]) * invZ[rg][r];
                atomicAdd(&tmps_l[s], val);
            }
        }
        cur ^= 1;
    }
#undef SC_ISSUE0
#undef SC_ISSUE2

    __syncthreads();
    for (int i = t; i < S_; i += 256)
        atomicAdd(&tmps[(size_t)bh_i * S_ + i], tmps_l[i]);
}

// ---------------------------------------------------------------------------
// Top-k (k=10) per (b,h); ties -> smaller index (matches jax.lax.top_k).
// ---------------------------------------------------------------------------
__global__ __launch_bounds__(256) void topk_kernel(
    const float* __restrict__ tmps, int* __restrict__ idxs)
{
    const int bh = blockIdx.x;
    const int t  = threadIdx.x;
    __shared__ float v[S_];
    __shared__ float rv[256];
    __shared__ int   ri[256];

    for (int i = t; i < S_; i += 256) v[i] = tmps[(size_t)bh * S_ + i];
    __syncthreads();

    for (int it = 0; it < TOPK_; ++it) {
        float best = -1e38f;
        int bi = 0x7fffffff;
        for (int s = t; s < S_; s += 256) {
            const float x = v[s];
            if (x > best) { best = x; bi = s; }
        }
        rv[t] = best; ri[t] = bi;
        __syncthreads();
        for (int k = 128; k > 0; k >>= 1) {
            if (t < k) {
                const float x = rv[t + k];
                const int  xi = ri[t + k];
                if (x > rv[t] || (x == rv[t] && xi < ri[t])) { rv[t] = x; ri[t] = xi; }
            }
            __syncthreads();
        }
        if (t == 0) {
            idxs[bh * TOPK_ + it] = ri[0];
            v[ri[0]] = -1e38f;
        }
        __syncthreads();
    }
}

// ---------------------------------------------------------------------------
// Gather selected K rows into tok[b][topk][D]
// ---------------------------------------------------------------------------
__global__ __launch_bounds__(256) void gather_kernel(
    const float* __restrict__ K, const int* __restrict__ idxs,
    float* __restrict__ tok)
{
    const int o = blockIdx.x * 256 + threadIdx.x;
    if (o >= B_ * TOPK_ * D_) return;
    const int d  = o & (D_ - 1);
    const int tt = (o >> 10) % TOPK_;
    const int b  = o / (D_ * TOPK_);
    const int h  = d >> 7;
    const int s  = idxs[(b * H_ + h) * TOPK_ + tt];
    tok[o] = K[(size_t)s * D_ + d];
}

// ---------------------------------------------------------------------------
extern "C" void kernel_launch(void* const* d_in, const int* in_sizes, int n_in,
                              void* d_out, int out_size, void* d_ws, size_t ws_size,
                              hipStream_t stream)
{
    const float* tgt = (const float*)d_in[0];
    const float* src = (const float*)d_in[1];
    const float* Wq  = (const float*)d_in[2];
    const float* bq  = (const float*)d_in[3];
    const float* Wk  = (const float*)d_in[4];
    const float* bk  = (const float*)d_in[5];
    const float* Wo  = (const float*)d_in[6];
    const float* bo  = (const float*)d_in[7];
    float* out = (float*)d_out;

    // workspace layout (bytes, all 256-aligned)
    char* ws = (char*)d_ws;
    size_t off = 0;
    float*          Kbuf = (float*)(ws + off);          off += (size_t)S_ * D_ * 4;
    float*          tmps = (float*)(ws + off);          off += (size_t)B_ * H_ * S_ * 4;
    int*            idxs = (int*)(ws + off);            off += (size_t)B_ * H_ * TOPK_ * 4;
    off = (off + 255) & ~(size_t)255;
    float*          tok  = (float*)(ws + off);          off += (size_t)B_ * TOPK_ * D_ * 4;
    unsigned short* Kh   = (unsigned short*)(ws + off); off += (size_t)1024 * D_ * 2;
    unsigned short* Kl   = (unsigned short*)(ws + off); off += (size_t)1024 * D_ * 2;
    unsigned short* WqTh = (unsigned short*)(ws + off); off += (size_t)D_ * D_ * 2;
    unsigned short* WqTl = (unsigned short*)(ws + off); off += (size_t)D_ * D_ * 2;
    unsigned short* WkTh = (unsigned short*)(ws + off); off += (size_t)D_ * D_ * 2;
    unsigned short* WkTl = (unsigned short*)(ws + off); off += (size_t)D_ * D_ * 2;
    unsigned short* Sh   = (unsigned short*)(ws + off); off += (size_t)1024 * D_ * 2;
    unsigned short* Sl   = (unsigned short*)(ws + off); off += (size_t)1024 * D_ * 2;
    unsigned short* planes = (unsigned short*)(ws + off);
    const size_t fixed_bytes = off;
    const size_t plane_elems_per_b = (size_t)L_ * D_;   // bf16 plane per batch
    // per batch: qh + ql = 2 planes x 4 MB = 8 MB

    int nb_fit = 1;
    if (ws_size > fixed_bytes) {
        size_t f = (ws_size - fixed_bytes) / (2 * plane_elems_per_b * 2);
        nb_fit = (f < 1) ? 1 : (f > 8 ? 8 : (int)f);
    }

    hipMemsetAsync(tmps, 0, (size_t)B_ * H_ * S_ * sizeof(float), stream);

    split_src_kernel<<<(1024 * D_) / (256 * 4), 256, 0, stream>>>(src, Sh, Sl);
    {
        dim3 g(D_ / 64, D_ / 64);
        splitWT_kernel<<<g, 256, 0, stream>>>(Wq, WqTh, WqTl);
        splitWT_kernel<<<g, 256, 0, stream>>>(Wk, WkTh, WkTl);
    }

    // K = src @ Wk + bk via 3-term MFMA (writes Kbuf f32 + Kh/Kl bf16)
    kproj_kernel<<<64, 256, 0, stream>>>(Sh, Sl, WkTh, WkTl, bk, Kbuf, Kh, Kl);

    for (int b0 = 0; b0 < B_; b0 += nb_fit) {
        int nb = (B_ - b0 < nb_fit) ? (B_ - b0) : nb_fit;
        unsigned short* qhb = planes;
        unsigned short* qlb = qhb + (size_t)nb_fit * plane_elems_per_b;

        qproj_kernel<<<nb * 128, 256, 0, stream>>>(
            tgt + (size_t)b0 * L_ * D_, WqTh, WqTl, bq, qhb, qlb);
        scores2p_kernel<<<nb * 64, 256, 0, stream>>>(qhb, qlb, Kh, Kl, tmps, b0);
    }

    topk_kernel<<<B_ * H_, 256, 0, stream>>>(tmps, idxs);
    gather_kernel<<<(B_ * TOPK_ * D_ + 255) / 256, 256, 0, stream>>>(Kbuf, idxs, tok);
    {
        dim3 g(D_ / 64, (B_ * TOPK_ + 63) / 64);
        gemm_bias_kernel<<<g, 256, 0, stream>>>(tok, Wo, bo, out, B_ * TOPK_, D_, D_);
    }
}